// Round 7
// baseline (599.874 us; speedup 1.0000x reference)
//
#include <hip/hip_runtime.h>
#include <hip/hip_fp16.h>

// DGCF single-layer, 2 routing iters (MI355X). fp32 in / fp32 out.
// R6 post-mortem: slicing halved FETCH but scattered v writes (WRITE 8.7->51.6MB),
// an extra pass, and 4x index traffic ate the win. R7: one slice per pinned pass
// (1.92MB << 4MB XCD L2), slice-major [intent][E] layouts so every non-gather
// stream is contiguous, Zn materialized fp16 (propZ) instead of recomputed.
//   propZ (pinned): Z1 slice accum from Ys -> Zn slice (l2norm'd, fp16)
//   attn  (pinned): dot(Zn[h], Tns[t]) -> v[i*E+k] fp16 (8B-contig writes)
//   softmax: 4-stream coalesced -> scores[i*E+e] fp16
//   outk  (pinned): acc = sum s*Y1s[t] -> out = 0.5*(X + dcol1*acc)
// Workspace 40.7 MB (< 46.72 MB proven available in R4).

#define NUSERS 30000
#define NN     60000
#define EE     800000
#define SL     ((size_t)NN * 16)   // elements per intent slice

__device__ __forceinline__ float getX(const float* __restrict__ Gu,
                                      const float* __restrict__ Gi,
                                      int n, int c) {
    return (n < NUSERS) ? Gu[n * 64 + c] : Gi[(n - NUSERS) * 64 + c];
}

__device__ __forceinline__ int clampN(int n) {
    return ((unsigned)n < (unsigned)NN) ? n : 0;
}

// Pinned-block index decode: blockIdx b -> intent i (XCD pair), node n.
__device__ __forceinline__ int pinnedNode(int b, int tid, int* i) {
    int xcd = b & 7;
    *i = xcd >> 1;
    int g = (b >> 3) * 2 + (xcd & 1);          // node-group in [0,15000)
    return g * 4 + (tid >> 6);
}

// ---- CSR build ----

__global__ void edge_count(const int* __restrict__ eh, int* __restrict__ deg0) {
    int e = blockIdx.x * blockDim.x + threadIdx.x;
    if (e >= EE) return;
    atomicAdd(&deg0[clampN(eh[e])], 1);
}

__global__ void scan_offsets(const int* __restrict__ deg0, int* __restrict__ offsets) {
    __shared__ int sums[1024];
    const int CH = (NN + 1023) / 1024;
    int tid = threadIdx.x;
    int base = tid * CH;
    int s = 0;
    for (int j = 0; j < CH; ++j) {
        int idx = base + j;
        if (idx < NN) s += deg0[idx];
    }
    sums[tid] = s;
    __syncthreads();
    for (int off = 1; off < 1024; off <<= 1) {
        int v = (tid >= off) ? sums[tid - off] : 0;
        __syncthreads();
        sums[tid] += v;
        __syncthreads();
    }
    int run = (tid == 0) ? 0 : sums[tid - 1];
    for (int j = 0; j < CH; ++j) {
        int idx = base + j;
        if (idx < NN) { offsets[idx] = run; run += deg0[idx]; }
    }
    if (tid == 1023) offsets[NN] = sums[1023];
}

__global__ void edge_scatter(const int* __restrict__ eh, const int* __restrict__ et,
                             const int* __restrict__ offsets, int* __restrict__ cursor,
                             int* __restrict__ csr_tail) {
    int e = blockIdx.x * blockDim.x + threadIdx.x;
    if (e >= EE) return;
    int h = clampN(eh[e]);
    int slot = offsets[h] + atomicAdd(&cursor[h], 1);
    if (slot < EE) csr_tail[slot] = clampN(et[e]);
}

// ---- node-side precompute ----

// Wave/node: Tns[i][n][ch] = tanh(x/|x|_i), Ys[i][n][ch] = dcol0*x  (fp16)
__global__ void prep0s(const float* __restrict__ Gu, const float* __restrict__ Gi,
                       const int* __restrict__ deg0,
                       __half* __restrict__ Tns, __half* __restrict__ Ys) {
    int n = blockIdx.x * 4 + (threadIdx.x >> 6);
    if (n >= NN) return;
    int lane = threadIdx.x & 63;
    int i = lane >> 4, ch = lane & 15;
    float x = getX(Gu, Gi, n, lane);
    float sx = x * x;
    #pragma unroll
    for (int m = 1; m < 16; m <<= 1) sx += __shfl_xor(sx, m, 64);
    float invx = rsqrtf(fmaxf(sx, 1e-12f));
    size_t a = (size_t)i * SL + (size_t)n * 16 + ch;
    Tns[a] = __float2half(tanhf(x * invx));
    float d0 = rsqrtf(fmaxf(0.25f * (float)deg0[n], 1e-30f));
    Ys[a] = __float2half(d0 * x);
}

// ---- pinned slice passes (wave = (node, intent); lanes = 4 edges x 16 ch) ----

// Z1 slice accumulate -> l2norm per (node,intent) -> Zn slice fp16 (coalesced).
__global__ void propZ(const int* __restrict__ offsets, const int* __restrict__ csr_tail,
                      const __half* __restrict__ Ys, __half* __restrict__ Zns) {
    int i;
    int n = pinnedNode(blockIdx.x, threadIdx.x, &i);
    int lane = threadIdx.x & 63;
    int seg = lane >> 4, ch = lane & 15;
    int s0 = offsets[n], s1 = offsets[n + 1];
    const __half* Yi = Ys + (size_t)i * SL;

    float acc = 0.f;
    for (int k = s0; k < s1; k += 4) {
        int kk = k + seg;
        int t = (kk < s1) ? csr_tail[kk] : 0;
        float y = __half2float(Yi[(size_t)t * 16 + ch]);
        acc += (kk < s1) ? y : 0.f;
    }
    acc += __shfl_xor(acc, 16, 64);
    acc += __shfl_xor(acc, 32, 64);
    float sz = acc * acc;
    #pragma unroll
    for (int m = 1; m < 16; m <<= 1) sz += __shfl_xor(sz, m, 64);
    float zn = acc * rsqrtf(fmaxf(sz, 1e-12f));
    if (seg == 0) Zns[(size_t)i * SL + (size_t)n * 16 + ch] = __float2half(zn);
}

// dot(Zn[h], Tns[t]) over 16 ch -> v[i*E + k] fp16 (8B-contiguous writes).
__global__ void attn(const int* __restrict__ offsets, const int* __restrict__ csr_tail,
                     const __half* __restrict__ Zns, const __half* __restrict__ Tns,
                     __half* __restrict__ v) {
    int i;
    int n = pinnedNode(blockIdx.x, threadIdx.x, &i);
    int lane = threadIdx.x & 63;
    int seg = lane >> 4, ch = lane & 15;
    int s0 = offsets[n], s1 = offsets[n + 1];
    const __half* Ti = Tns + (size_t)i * SL;
    float zn = __half2float(Zns[(size_t)i * SL + (size_t)n * 16 + ch]);
    __half* vi = v + (size_t)i * EE;

    for (int k = s0; k < s1; k += 4) {
        int kk = k + seg;
        int t = (kk < s1) ? csr_tail[kk] : 0;
        float p = zn * __half2float(Ti[(size_t)t * 16 + ch]);
        #pragma unroll
        for (int m = 1; m < 16; m <<= 1) p += __shfl_xor(p, m, 64);
        if (kk < s1 && ch == 0) vi[kk] = __float2half(p);
    }
}

// Edge-parallel 4-way softmax over slice-major v -> slice-major fp16 scores.
__global__ void softmax_kernel(const __half* __restrict__ v, __half* __restrict__ scores) {
    int e = blockIdx.x * blockDim.x + threadIdx.x;
    if (e >= EE) return;
    float v0 = __half2float(v[e]);
    float v1 = __half2float(v[EE + e]);
    float v2 = __half2float(v[2 * EE + e]);
    float v3 = __half2float(v[3 * EE + e]);
    float mx = fmaxf(fmaxf(v0, v1), fmaxf(v2, v3));
    float e0 = __expf(v0 - mx), e1 = __expf(v1 - mx);
    float e2 = __expf(v2 - mx), e3 = __expf(v3 - mx);
    float inv = 1.f / (e0 + e1 + e2 + e3);
    scores[e]          = __float2half(e0 * inv);
    scores[EE + e]     = __float2half(e1 * inv);
    scores[2 * EE + e] = __float2half(e2 * inv);
    scores[3 * EE + e] = __float2half(e3 * inv);
}

// Wave/node: deg1[n][i] = sum of scores over segment -> dcol1 = rsqrt.
__global__ void dcol1_kernel(const int* __restrict__ offsets, const __half* __restrict__ scores,
                             float* __restrict__ dcol1) {
    int n = blockIdx.x * 4 + (threadIdx.x >> 6);
    if (n >= NN) return;
    int lane = threadIdx.x & 63;
    int j = lane >> 2, i = lane & 3;
    int s0 = offsets[n], s1 = offsets[n + 1];
    const __half* si = scores + (size_t)i * EE;
    float sum = 0.f;
    for (int k = s0 + j; k < s1; k += 16) sum += __half2float(si[k]);
    #pragma unroll
    for (int m = 4; m < 64; m <<= 1) sum += __shfl_xor(sum, m, 64);
    if (j == 0) dcol1[n * 4 + i] = rsqrtf(fmaxf(sum, 1e-30f));
}

// Y1s[i][n][ch] = dcol1[n][i] * X[n][i*16+ch]  (fp16, sliced)
__global__ void build_Y1s(const float* __restrict__ Gu, const float* __restrict__ Gi,
                          const float* __restrict__ dcol1, __half* __restrict__ Y1s) {
    int idx = blockIdx.x * blockDim.x + threadIdx.x;
    if (idx >= NN * 64) return;
    int i = idx / (NN * 16);
    int r = idx - i * (NN * 16);
    int n = r >> 4, ch = r & 15;
    Y1s[idx] = __float2half(dcol1[n * 4 + i] * getX(Gu, Gi, n, i * 16 + ch));
}

// acc = sum s*Y1s[t] -> out = 0.5*(x + dcol1*acc). Score reads contiguous.
__global__ void outk(const int* __restrict__ offsets, const int* __restrict__ csr_tail,
                     const __half* __restrict__ Y1s, const __half* __restrict__ scores,
                     const float* __restrict__ dcol1,
                     const float* __restrict__ Gu, const float* __restrict__ Gi,
                     float* __restrict__ out) {
    int i;
    int n = pinnedNode(blockIdx.x, threadIdx.x, &i);
    int lane = threadIdx.x & 63;
    int seg = lane >> 4, ch = lane & 15;
    int s0 = offsets[n], s1 = offsets[n + 1];
    const __half* Yi = Y1s + (size_t)i * SL;
    const __half* si = scores + (size_t)i * EE;

    float acc = 0.f;
    for (int k = s0; k < s1; k += 4) {
        int kk = k + seg;
        int t = (kk < s1) ? csr_tail[kk] : 0;
        float s = (kk < s1) ? __half2float(si[kk]) : 0.f;
        acc += s * __half2float(Yi[(size_t)t * 16 + ch]);
    }
    acc += __shfl_xor(acc, 16, 64);
    acc += __shfl_xor(acc, 32, 64);
    if (seg == 0) {
        int c = i * 16 + ch;
        float x = getX(Gu, Gi, n, c);
        out[n * 64 + c] = 0.5f * (x + dcol1[n * 4 + i] * acc);
    }
}

// ---- launch ----

extern "C" void kernel_launch(void* const* d_in, const int* in_sizes, int n_in,
                              void* d_out, int out_size, void* d_ws, size_t ws_size,
                              hipStream_t stream) {
    const float* Gu = (const float*)d_in[0];
    const float* Gi = (const float*)d_in[1];
    const int* eh = (const int*)d_in[2];
    const int* et = (const int*)d_in[3];
    float* out = (float*)d_out;

    char* p = (char*)d_ws;
    __half* v        = (__half*)p;     p += (size_t)EE * 4 * 2;       // 6.4 MB
    __half* scores   = (__half*)p;     p += (size_t)EE * 4 * 2;       // 6.4 MB
    int*    csr_tail = (int*)p;        p += (size_t)EE * 4;           // 3.2 MB
    int*    offsets  = (int*)p;        p += ((size_t)(NN + 1) * 4 + 15) / 16 * 16;
    int*    deg0     = (int*)p;        p += (size_t)NN * 4;
    int*    cursor   = (int*)p;        p += (size_t)NN * 4;
    float*  dcol1    = (float*)p;      p += (size_t)NN * 4 * 4;
    __half* Ys       = (__half*)p;     p += 4 * SL * 2;               // 7.68 MB (Y1s reuses)
    __half* Tns      = (__half*)p;     p += 4 * SL * 2;               // 7.68 MB
    __half* Zns      = (__half*)p;     // 7.68 MB -> total ~40.7 MB
    __half* Y1s      = Ys;

    const int nk_blocks   = (NN * 64 + 255) / 256;
    const int edge_blocks = (EE + 255) / 256;
    const int nw_blocks   = (NN + 3) / 4;
    const int sl_blocks   = NN;        // 15000 node-groups x 4 intents (pinned)

    // CSR build
    hipMemsetAsync(deg0, 0, NN * sizeof(int), stream);
    hipMemsetAsync(cursor, 0, NN * sizeof(int), stream);
    edge_count<<<edge_blocks, 256, 0, stream>>>(eh, deg0);
    scan_offsets<<<1, 1024, 0, stream>>>(deg0, offsets);
    edge_scatter<<<edge_blocks, 256, 0, stream>>>(eh, et, offsets, cursor, csr_tail);

    // iter 0: sliced tables, pinned Z1 accumulate, pinned attention dots
    prep0s<<<nw_blocks, 256, 0, stream>>>(Gu, Gi, deg0, Tns, Ys);
    propZ<<<sl_blocks, 256, 0, stream>>>(offsets, csr_tail, Ys, Zns);
    attn<<<sl_blocks, 256, 0, stream>>>(offsets, csr_tail, Zns, Tns, v);
    softmax_kernel<<<edge_blocks, 256, 0, stream>>>(v, scores);

    // iter 1: dcol1, sliced Y1, pinned propagate+finalize
    dcol1_kernel<<<nw_blocks, 256, 0, stream>>>(offsets, scores, dcol1);
    build_Y1s<<<nk_blocks, 256, 0, stream>>>(Gu, Gi, dcol1, Y1s);
    outk<<<sl_blocks, 256, 0, stream>>>(offsets, csr_tail, Y1s, scores, dcol1, Gu, Gi, out);
}

// Round 9
// 547.018 us; speedup vs baseline: 1.0966x; 1.0966x over previous
//
#include <hip/hip_runtime.h>
#include <hip/hip_fp16.h>

// DGCF single-layer, 2 routing iters (MI355X). fp32 in / fp32 out.
// R8 post-mortem: __shfl(tails, j) executed under divergent per-seg trip
// counts -> source lane could be in an exited seg-group (EXEC=0) -> undefined
// bpermute data -> ~12% of nodes (deg>16) gathered node 0 (absmax 2.8e-2).
// R9 fix: uniform trip count (iters = ceil(cnt/4), j = 4r+seg, all 64 lanes
// active every iteration); predicate accumulates/writes on j < cnt only.
// Structure otherwise identical to R8:
//  - tail preload: one coalesced 64-lane csr_tail load/wave, indices via shfl
//  - fused propZ+attn (zn in regs), fused softmax+dcol1+Y1s
//  - slice-major tables [intent][N][16] fp16, edge streams [intent][E]
//  - pinned blockIdx%8 -> XCD -> intent mapping for L2 residency

#define NUSERS 30000
#define NN     60000
#define EE     800000
#define SL     ((size_t)NN * 16)   // elements per intent slice

__device__ __forceinline__ float getX(const float* __restrict__ Gu,
                                      const float* __restrict__ Gi,
                                      int n, int c) {
    return (n < NUSERS) ? Gu[n * 64 + c] : Gi[(n - NUSERS) * 64 + c];
}

__device__ __forceinline__ int clampN(int n) {
    return ((unsigned)n < (unsigned)NN) ? n : 0;
}

// Pinned-block index decode: blockIdx b -> intent i (XCD pair), node n.
__device__ __forceinline__ int pinnedNode(int b, int tid, int* i) {
    int xcd = b & 7;
    *i = xcd >> 1;
    int g = (b >> 3) * 2 + (xcd & 1);          // node-group in [0,15000)
    return g * 4 + (tid >> 6);
}

// ---- CSR build ----

__global__ void edge_count(const int* __restrict__ eh, int* __restrict__ deg0) {
    int e = blockIdx.x * blockDim.x + threadIdx.x;
    if (e >= EE) return;
    atomicAdd(&deg0[clampN(eh[e])], 1);
}

__global__ void scan_offsets(const int* __restrict__ deg0, int* __restrict__ offsets) {
    __shared__ int sums[1024];
    const int CH = (NN + 1023) / 1024;
    int tid = threadIdx.x;
    int base = tid * CH;
    int s = 0;
    for (int j = 0; j < CH; ++j) {
        int idx = base + j;
        if (idx < NN) s += deg0[idx];
    }
    sums[tid] = s;
    __syncthreads();
    for (int off = 1; off < 1024; off <<= 1) {
        int v = (tid >= off) ? sums[tid - off] : 0;
        __syncthreads();
        sums[tid] += v;
        __syncthreads();
    }
    int run = (tid == 0) ? 0 : sums[tid - 1];
    for (int j = 0; j < CH; ++j) {
        int idx = base + j;
        if (idx < NN) { offsets[idx] = run; run += deg0[idx]; }
    }
    if (tid == 1023) offsets[NN] = sums[1023];
}

__global__ void edge_scatter(const int* __restrict__ eh, const int* __restrict__ et,
                             const int* __restrict__ offsets, int* __restrict__ cursor,
                             int* __restrict__ csr_tail) {
    int e = blockIdx.x * blockDim.x + threadIdx.x;
    if (e >= EE) return;
    int h = clampN(eh[e]);
    int slot = offsets[h] + atomicAdd(&cursor[h], 1);
    if (slot < EE) csr_tail[slot] = clampN(et[e]);
}

// ---- node-side precompute ----

// Wave/node: Tns[i][n][ch] = tanh(x/|x|_i), Ys[i][n][ch] = dcol0*x  (fp16)
__global__ void prep0s(const float* __restrict__ Gu, const float* __restrict__ Gi,
                       const int* __restrict__ deg0,
                       __half* __restrict__ Tns, __half* __restrict__ Ys) {
    int n = blockIdx.x * 4 + (threadIdx.x >> 6);
    if (n >= NN) return;
    int lane = threadIdx.x & 63;
    int i = lane >> 4, ch = lane & 15;
    float x = getX(Gu, Gi, n, lane);
    float sx = x * x;
    #pragma unroll
    for (int m = 1; m < 16; m <<= 1) sx += __shfl_xor(sx, m, 64);
    float invx = rsqrtf(fmaxf(sx, 1e-12f));
    size_t a = (size_t)i * SL + (size_t)n * 16 + ch;
    Tns[a] = __float2half(tanhf(x * invx));
    float d0 = rsqrtf(fmaxf(0.25f * (float)deg0[n], 1e-30f));
    Ys[a] = __float2half(d0 * x);
}

// ---- fused pinned pass: Z1 accumulate + l2norm + attention dots ----
// Wave = (node, intent); lanes = 4 edge-slots x 16 channels.
// Uniform trip counts: ALL 64 lanes execute every iteration (shfl sources
// always active); accumulates/writes predicated on j < cnt.
__global__ void fused_attn(const int* __restrict__ offsets, const int* __restrict__ csr_tail,
                           const __half* __restrict__ Ys, const __half* __restrict__ Tns,
                           __half* __restrict__ v) {
    int i;
    int n = pinnedNode(blockIdx.x, threadIdx.x, &i);
    int lane = threadIdx.x & 63;
    int seg = lane >> 4, ch = lane & 15;
    int s0 = offsets[n], s1 = offsets[n + 1];
    const __half* Yi = Ys + (size_t)i * SL;
    const __half* Ti = Tns + (size_t)i * SL;

    // phase 1: Z1 slice accumulate (0.25 + head dcol0 dropped -- l2norm invariant)
    float acc = 0.f;
    for (int base = s0; base < s1; base += 64) {
        int kk = base + lane;
        int tails = (kk < s1) ? csr_tail[kk] : 0;   // one coalesced load; pad lanes -> 0
        int cnt = min(64, s1 - base);
        int iters = (cnt + 3) >> 2;                 // wave-uniform
        for (int r = 0; r < iters; ++r) {
            int j = 4 * r + seg;                    // < 64 always
            int t = __shfl(tails, j, 64);           // all lanes active
            float y = __half2float(Yi[(size_t)t * 16 + ch]);
            acc += (j < cnt) ? y : 0.f;
        }
    }
    acc += __shfl_xor(acc, 16, 64);
    acc += __shfl_xor(acc, 32, 64);
    float sz = acc * acc;
    #pragma unroll
    for (int m = 1; m < 16; m <<= 1) sz += __shfl_xor(sz, m, 64);
    float zn = acc * rsqrtf(fmaxf(sz, 1e-12f));   // l2norm(Z1)_i[ch], uniform over seg

    // phase 2: dots vs Tn[t] -> v[i*E + k]
    __half* vi = v + (size_t)i * EE;
    for (int base = s0; base < s1; base += 64) {
        int kk = base + lane;
        int tails = (kk < s1) ? csr_tail[kk] : 0;
        int cnt = min(64, s1 - base);
        int iters = (cnt + 3) >> 2;
        for (int r = 0; r < iters; ++r) {
            int j = 4 * r + seg;
            int t = __shfl(tails, j, 64);
            float p = zn * __half2float(Ti[(size_t)t * 16 + ch]);
            #pragma unroll
            for (int m = 1; m < 16; m <<= 1) p += __shfl_xor(p, m, 64);
            if (j < cnt && ch == 0) vi[base + j] = __float2half(p);
        }
    }
}

// ---- fused softmax + deg1 + dcol1 + Y1s build (wave per node) ----
__global__ void sm_dcol_y1(const int* __restrict__ offsets, const __half* __restrict__ v,
                           __half* __restrict__ scores, float* __restrict__ dcol1,
                           const float* __restrict__ Gu, const float* __restrict__ Gi,
                           __half* __restrict__ Y1s) {
    int n = blockIdx.x * 4 + (threadIdx.x >> 6);
    if (n >= NN) return;
    int lane = threadIdx.x & 63;
    int s0 = offsets[n], s1 = offsets[n + 1];
    float sum0 = 0.f, sum1 = 0.f, sum2 = 0.f, sum3 = 0.f;
    for (int k = s0 + lane; k < s1; k += 64) {
        float v0 = __half2float(v[k]);
        float v1 = __half2float(v[EE + k]);
        float v2 = __half2float(v[2 * EE + k]);
        float v3 = __half2float(v[3 * EE + k]);
        float mx = fmaxf(fmaxf(v0, v1), fmaxf(v2, v3));
        float e0 = __expf(v0 - mx), e1 = __expf(v1 - mx);
        float e2 = __expf(v2 - mx), e3 = __expf(v3 - mx);
        float inv = 1.f / (e0 + e1 + e2 + e3);
        e0 *= inv; e1 *= inv; e2 *= inv; e3 *= inv;
        scores[k]          = __float2half(e0);
        scores[EE + k]     = __float2half(e1);
        scores[2 * EE + k] = __float2half(e2);
        scores[3 * EE + k] = __float2half(e3);
        sum0 += e0; sum1 += e1; sum2 += e2; sum3 += e3;
    }
    #pragma unroll
    for (int m = 1; m < 64; m <<= 1) {
        sum0 += __shfl_xor(sum0, m, 64);
        sum1 += __shfl_xor(sum1, m, 64);
        sum2 += __shfl_xor(sum2, m, 64);
        sum3 += __shfl_xor(sum3, m, 64);
    }
    int i = lane >> 4, ch = lane & 15;
    float dsel = (i == 0) ? sum0 : (i == 1) ? sum1 : (i == 2) ? sum2 : sum3;
    float d = rsqrtf(fmaxf(dsel, 1e-30f));
    if (lane < 4) {
        float ds = (lane == 0) ? sum0 : (lane == 1) ? sum1 : (lane == 2) ? sum2 : sum3;
        dcol1[n * 4 + lane] = rsqrtf(fmaxf(ds, 1e-30f));
    }
    float x = getX(Gu, Gi, n, lane);
    Y1s[(size_t)i * SL + (size_t)n * 16 + ch] = __float2half(d * x);
}

// ---- pinned output pass: Z2 gather + finalize ----
__global__ void outk(const int* __restrict__ offsets, const int* __restrict__ csr_tail,
                     const __half* __restrict__ Y1s, const __half* __restrict__ scores,
                     const float* __restrict__ dcol1,
                     const float* __restrict__ Gu, const float* __restrict__ Gi,
                     float* __restrict__ out) {
    int i;
    int n = pinnedNode(blockIdx.x, threadIdx.x, &i);
    int lane = threadIdx.x & 63;
    int seg = lane >> 4, ch = lane & 15;
    int s0 = offsets[n], s1 = offsets[n + 1];
    const __half* Yi = Y1s + (size_t)i * SL;
    const __half* si = scores + (size_t)i * EE;

    float acc = 0.f;
    for (int base = s0; base < s1; base += 64) {
        int kk = base + lane;
        int tails = (kk < s1) ? csr_tail[kk] : 0;   // coalesced; pad lanes -> 0
        int cnt = min(64, s1 - base);
        int iters = (cnt + 3) >> 2;                 // wave-uniform
        for (int r = 0; r < iters; ++r) {
            int j = 4 * r + seg;
            int t = __shfl(tails, j, 64);           // all lanes active
            float s = (j < cnt) ? __half2float(si[base + j]) : 0.f;
            acc += s * __half2float(Yi[(size_t)t * 16 + ch]);
        }
    }
    acc += __shfl_xor(acc, 16, 64);
    acc += __shfl_xor(acc, 32, 64);
    if (seg == 0) {
        int c = i * 16 + ch;
        float x = getX(Gu, Gi, n, c);
        out[n * 64 + c] = 0.5f * (x + dcol1[n * 4 + i] * acc);
    }
}

// ---- launch ----

extern "C" void kernel_launch(void* const* d_in, const int* in_sizes, int n_in,
                              void* d_out, int out_size, void* d_ws, size_t ws_size,
                              hipStream_t stream) {
    const float* Gu = (const float*)d_in[0];
    const float* Gi = (const float*)d_in[1];
    const int* eh = (const int*)d_in[2];
    const int* et = (const int*)d_in[3];
    float* out = (float*)d_out;

    char* p = (char*)d_ws;
    __half* v        = (__half*)p;     p += (size_t)EE * 4 * 2;       // 6.4 MB
    __half* scores   = (__half*)p;     p += (size_t)EE * 4 * 2;       // 6.4 MB
    int*    csr_tail = (int*)p;        p += (size_t)EE * 4;           // 3.2 MB
    int*    offsets  = (int*)p;        p += ((size_t)(NN + 1) * 4 + 15) / 16 * 16;
    int*    deg0     = (int*)p;        p += (size_t)NN * 4;
    int*    cursor   = (int*)p;        p += (size_t)NN * 4;
    float*  dcol1    = (float*)p;      p += (size_t)NN * 4 * 4;
    __half* Ys       = (__half*)p;     p += 4 * SL * 2;               // 7.68 MB
    __half* Tns      = (__half*)p;     // 7.68 MB -> total ~33 MB
    __half* Y1s      = Ys;             // reused after fused_attn

    const int edge_blocks = (EE + 255) / 256;
    const int nw_blocks   = (NN + 3) / 4;
    const int sl_blocks   = NN;        // 15000 node-groups x 4 intents (pinned)

    // CSR build
    hipMemsetAsync(deg0, 0, NN * sizeof(int), stream);
    hipMemsetAsync(cursor, 0, NN * sizeof(int), stream);
    edge_count<<<edge_blocks, 256, 0, stream>>>(eh, deg0);
    scan_offsets<<<1, 1024, 0, stream>>>(deg0, offsets);
    edge_scatter<<<edge_blocks, 256, 0, stream>>>(eh, et, offsets, cursor, csr_tail);

    // iter 0: sliced tables + fused Z1/attention
    prep0s<<<nw_blocks, 256, 0, stream>>>(Gu, Gi, deg0, Tns, Ys);
    fused_attn<<<sl_blocks, 256, 0, stream>>>(offsets, csr_tail, Ys, Tns, v);

    // softmax + dcol1 + Y1s in one pass
    sm_dcol_y1<<<nw_blocks, 256, 0, stream>>>(offsets, v, scores, dcol1, Gu, Gi, Y1s);

    // iter 1 propagate + finalize
    outk<<<sl_blocks, 256, 0, stream>>>(offsets, csr_tail, Y1s, scores, dcol1, Gu, Gi, out);
}

// Round 10
// 452.978 us; speedup vs baseline: 1.3243x; 1.2076x over previous
//
#include <hip/hip_runtime.h>
#include <hip/hip_fp16.h>

// DGCF single-layer, 2 routing iters (MI355X). fp32 in / fp32 out.
// R9 post-mortem: fused_attn ~790 VALU-cyc/wave — per-edge bpermute + 4-shuffle
// butterfly + ~8 serial iterations (4-edge parallelism) dominate. R10: lane
// re-map to 16 edges x 4 channels per wave:
//  - tail/score loads: direct coalesced lane loads (no bpermute)
//  - channel dot: 2 fp32 shuffles (xor 1,2); cross-edge Z reduce: one 8-shuffle
//    butterfly (xor 4..32) per wave, not per edge
//  - packed __hfma2; 1 iteration covers deg<=16 (58% of nodes)
// outk: fp32 per-lane accum, 16-shuffle reduce, float4 stores.
// Unchanged from R9 (passing): CSR build, prep0s, sm_dcol_y1, slice-major
// [intent][N][16] fp16 tables, [intent][E] edge streams, blockIdx%8 XCD pinning.

#define NUSERS 30000
#define NN     60000
#define EE     800000
#define SL     ((size_t)NN * 16)   // elements per intent slice

__device__ __forceinline__ float getX(const float* __restrict__ Gu,
                                      const float* __restrict__ Gi,
                                      int n, int c) {
    return (n < NUSERS) ? Gu[n * 64 + c] : Gi[(n - NUSERS) * 64 + c];
}

__device__ __forceinline__ int clampN(int n) {
    return ((unsigned)n < (unsigned)NN) ? n : 0;
}

__device__ __forceinline__ __half2 shfl_xor_h2(__half2 x, int m) {
    int xi = __builtin_bit_cast(int, x);
    xi = __shfl_xor(xi, m, 64);
    return __builtin_bit_cast(__half2, xi);
}

// Pinned-block index decode: blockIdx b -> intent i (XCD pair), node n.
__device__ __forceinline__ int pinnedNode(int b, int tid, int* i) {
    int xcd = b & 7;
    *i = xcd >> 1;
    int g = (b >> 3) * 2 + (xcd & 1);          // node-group in [0,15000)
    return g * 4 + (tid >> 6);
}

// ---- CSR build ----

__global__ void edge_count(const int* __restrict__ eh, int* __restrict__ deg0) {
    int e = blockIdx.x * blockDim.x + threadIdx.x;
    if (e >= EE) return;
    atomicAdd(&deg0[clampN(eh[e])], 1);
}

__global__ void scan_offsets(const int* __restrict__ deg0, int* __restrict__ offsets) {
    __shared__ int sums[1024];
    const int CH = (NN + 1023) / 1024;
    int tid = threadIdx.x;
    int base = tid * CH;
    int s = 0;
    for (int j = 0; j < CH; ++j) {
        int idx = base + j;
        if (idx < NN) s += deg0[idx];
    }
    sums[tid] = s;
    __syncthreads();
    for (int off = 1; off < 1024; off <<= 1) {
        int v = (tid >= off) ? sums[tid - off] : 0;
        __syncthreads();
        sums[tid] += v;
        __syncthreads();
    }
    int run = (tid == 0) ? 0 : sums[tid - 1];
    for (int j = 0; j < CH; ++j) {
        int idx = base + j;
        if (idx < NN) { offsets[idx] = run; run += deg0[idx]; }
    }
    if (tid == 1023) offsets[NN] = sums[1023];
}

__global__ void edge_scatter(const int* __restrict__ eh, const int* __restrict__ et,
                             const int* __restrict__ offsets, int* __restrict__ cursor,
                             int* __restrict__ csr_tail) {
    int e = blockIdx.x * blockDim.x + threadIdx.x;
    if (e >= EE) return;
    int h = clampN(eh[e]);
    int slot = offsets[h] + atomicAdd(&cursor[h], 1);
    if (slot < EE) csr_tail[slot] = clampN(et[e]);
}

// ---- node-side precompute ----

// Wave/node: Tns[i][n][ch] = tanh(x/|x|_i), Ys[i][n][ch] = dcol0*x  (fp16)
__global__ void prep0s(const float* __restrict__ Gu, const float* __restrict__ Gi,
                       const int* __restrict__ deg0,
                       __half* __restrict__ Tns, __half* __restrict__ Ys) {
    int n = blockIdx.x * 4 + (threadIdx.x >> 6);
    if (n >= NN) return;
    int lane = threadIdx.x & 63;
    int i = lane >> 4, ch = lane & 15;
    float x = getX(Gu, Gi, n, lane);
    float sx = x * x;
    #pragma unroll
    for (int m = 1; m < 16; m <<= 1) sx += __shfl_xor(sx, m, 64);
    float invx = rsqrtf(fmaxf(sx, 1e-12f));
    size_t a = (size_t)i * SL + (size_t)n * 16 + ch;
    Tns[a] = __float2half(tanhf(x * invx));
    float d0 = rsqrtf(fmaxf(0.25f * (float)deg0[n], 1e-30f));
    Ys[a] = __float2half(d0 * x);
}

// ---- fused pinned pass: Z1 accumulate + l2norm + attention dots ----
// Wave = (node, intent); lane = (edge slot e4 = lane>>2) x (ch-quad cp = lane&3).
__global__ void fused_attn(const int* __restrict__ offsets, const int* __restrict__ csr_tail,
                           const __half* __restrict__ Ys, const __half* __restrict__ Tns,
                           __half* __restrict__ v) {
    int i;
    int n = pinnedNode(blockIdx.x, threadIdx.x, &i);
    int lane = threadIdx.x & 63;
    int e4 = lane >> 2, cp = lane & 3;
    int s0 = offsets[n], s1 = offsets[n + 1];
    const __half* Yi = Ys + (size_t)i * SL;
    const __half* Ti = Tns + (size_t)i * SL;
    const __half2 h2z = __floats2half2_rn(0.f, 0.f);

    // phase 1: Z accumulate, 4 channels (2 half2) per lane, 16 edges/iter.
    __half2 z0 = h2z, z1 = h2z;
    for (int base = s0; base < s1; base += 16) {
        int kk = base + e4;
        bool act = kk < s1;
        int t = act ? csr_tail[kk] : 0;
        const __half2* row = (const __half2*)(Yi + (size_t)t * 16 + cp * 4);
        __half2 a = row[0], b = row[1];
        z0 = __hadd2(z0, act ? a : h2z);
        z1 = __hadd2(z1, act ? b : h2z);
    }
    // reduce across the 16 edge slots (xor lane bits 2..5); all lanes active
    #pragma unroll
    for (int m = 4; m < 64; m <<= 1) {
        z0 = __hadd2(z0, shfl_xor_h2(z0, m));
        z1 = __hadd2(z1, shfl_xor_h2(z1, m));
    }
    // per-intent sumsq: own 4 ch + xor 1,2 across ch-quads
    float2 f0 = __half22float2(z0), f1 = __half22float2(z1);
    float ss = f0.x * f0.x + f0.y * f0.y + f1.x * f1.x + f1.y * f1.y;
    ss += __shfl_xor(ss, 1, 64);
    ss += __shfl_xor(ss, 2, 64);
    float inv = rsqrtf(fmaxf(ss, 1e-12f));
    __half2 zn0 = __floats2half2_rn(f0.x * inv, f0.y * inv);
    __half2 zn1 = __floats2half2_rn(f1.x * inv, f1.y * inv);

    // phase 2: dot(zn, Tn[t]) per edge -> v[i*E + k]
    __half* vi = v + (size_t)i * EE;
    for (int base = s0; base < s1; base += 16) {
        int kk = base + e4;
        bool act = kk < s1;
        int t = act ? csr_tail[kk] : 0;
        const __half2* row = (const __half2*)(Ti + (size_t)t * 16 + cp * 4);
        __half2 d2 = __hmul2(zn0, row[0]);
        d2 = __hfma2(zn1, row[1], d2);
        float2 df = __half22float2(d2);
        float p = df.x + df.y;
        p += __shfl_xor(p, 1, 64);
        p += __shfl_xor(p, 2, 64);
        if (act && cp == 0) vi[kk] = __float2half(p);
    }
}

// ---- fused softmax + deg1 + dcol1 + Y1s build (wave per node) ----
__global__ void sm_dcol_y1(const int* __restrict__ offsets, const __half* __restrict__ v,
                           __half* __restrict__ scores, float* __restrict__ dcol1,
                           const float* __restrict__ Gu, const float* __restrict__ Gi,
                           __half* __restrict__ Y1s) {
    int n = blockIdx.x * 4 + (threadIdx.x >> 6);
    if (n >= NN) return;
    int lane = threadIdx.x & 63;
    int s0 = offsets[n], s1 = offsets[n + 1];
    float sum0 = 0.f, sum1 = 0.f, sum2 = 0.f, sum3 = 0.f;
    for (int k = s0 + lane; k < s1; k += 64) {
        float v0 = __half2float(v[k]);
        float v1 = __half2float(v[EE + k]);
        float v2 = __half2float(v[2 * EE + k]);
        float v3 = __half2float(v[3 * EE + k]);
        float mx = fmaxf(fmaxf(v0, v1), fmaxf(v2, v3));
        float e0 = __expf(v0 - mx), e1 = __expf(v1 - mx);
        float e2 = __expf(v2 - mx), e3 = __expf(v3 - mx);
        float inv = 1.f / (e0 + e1 + e2 + e3);
        e0 *= inv; e1 *= inv; e2 *= inv; e3 *= inv;
        scores[k]          = __float2half(e0);
        scores[EE + k]     = __float2half(e1);
        scores[2 * EE + k] = __float2half(e2);
        scores[3 * EE + k] = __float2half(e3);
        sum0 += e0; sum1 += e1; sum2 += e2; sum3 += e3;
    }
    #pragma unroll
    for (int m = 1; m < 64; m <<= 1) {
        sum0 += __shfl_xor(sum0, m, 64);
        sum1 += __shfl_xor(sum1, m, 64);
        sum2 += __shfl_xor(sum2, m, 64);
        sum3 += __shfl_xor(sum3, m, 64);
    }
    int i = lane >> 4, ch = lane & 15;
    float dsel = (i == 0) ? sum0 : (i == 1) ? sum1 : (i == 2) ? sum2 : sum3;
    float d = rsqrtf(fmaxf(dsel, 1e-30f));
    if (lane < 4) {
        float ds = (lane == 0) ? sum0 : (lane == 1) ? sum1 : (lane == 2) ? sum2 : sum3;
        dcol1[n * 4 + lane] = rsqrtf(fmaxf(ds, 1e-30f));
    }
    float x = getX(Gu, Gi, n, lane);
    Y1s[(size_t)i * SL + (size_t)n * 16 + ch] = __float2half(d * x);
}

// ---- pinned output pass: Z2 gather + finalize ----
// Lane = (edge slot e4) x (ch-quad cp); fp32 per-lane accum; float4 stores.
__global__ void outk(const int* __restrict__ offsets, const int* __restrict__ csr_tail,
                     const __half* __restrict__ Y1s, const __half* __restrict__ scores,
                     const float* __restrict__ dcol1,
                     const float* __restrict__ Gu, const float* __restrict__ Gi,
                     float* __restrict__ out) {
    int i;
    int n = pinnedNode(blockIdx.x, threadIdx.x, &i);
    int lane = threadIdx.x & 63;
    int e4 = lane >> 2, cp = lane & 3;
    int s0 = offsets[n], s1 = offsets[n + 1];
    const __half* Yi = Y1s + (size_t)i * SL;
    const __half* si = scores + (size_t)i * EE;

    float a0 = 0.f, a1 = 0.f, a2 = 0.f, a3 = 0.f;
    for (int base = s0; base < s1; base += 16) {
        int kk = base + e4;
        bool act = kk < s1;
        int t = act ? csr_tail[kk] : 0;
        float s = act ? __half2float(si[kk]) : 0.f;
        const __half2* row = (const __half2*)(Yi + (size_t)t * 16 + cp * 4);
        float2 r0 = __half22float2(row[0]), r1 = __half22float2(row[1]);
        a0 += s * r0.x; a1 += s * r0.y; a2 += s * r1.x; a3 += s * r1.y;
    }
    #pragma unroll
    for (int m = 4; m < 64; m <<= 1) {
        a0 += __shfl_xor(a0, m, 64);
        a1 += __shfl_xor(a1, m, 64);
        a2 += __shfl_xor(a2, m, 64);
        a3 += __shfl_xor(a3, m, 64);
    }
    if (e4 == 0) {
        int c = i * 16 + cp * 4;
        const float* xr = (n < NUSERS) ? (Gu + n * 64 + c) : (Gi + (n - NUSERS) * 64 + c);
        float4 x4 = *(const float4*)xr;
        float d = dcol1[n * 4 + i];
        float4 o;
        o.x = 0.5f * (x4.x + d * a0);
        o.y = 0.5f * (x4.y + d * a1);
        o.z = 0.5f * (x4.z + d * a2);
        o.w = 0.5f * (x4.w + d * a3);
        *(float4*)(out + (size_t)n * 64 + c) = o;
    }
}

// ---- launch ----

extern "C" void kernel_launch(void* const* d_in, const int* in_sizes, int n_in,
                              void* d_out, int out_size, void* d_ws, size_t ws_size,
                              hipStream_t stream) {
    const float* Gu = (const float*)d_in[0];
    const float* Gi = (const float*)d_in[1];
    const int* eh = (const int*)d_in[2];
    const int* et = (const int*)d_in[3];
    float* out = (float*)d_out;

    char* p = (char*)d_ws;
    __half* v        = (__half*)p;     p += (size_t)EE * 4 * 2;       // 6.4 MB
    __half* scores   = (__half*)p;     p += (size_t)EE * 4 * 2;       // 6.4 MB
    int*    csr_tail = (int*)p;        p += (size_t)EE * 4;           // 3.2 MB
    int*    offsets  = (int*)p;        p += ((size_t)(NN + 1) * 4 + 15) / 16 * 16;
    int*    deg0     = (int*)p;        p += (size_t)NN * 4;
    int*    cursor   = (int*)p;        p += (size_t)NN * 4;
    float*  dcol1    = (float*)p;      p += (size_t)NN * 4 * 4;
    __half* Ys       = (__half*)p;     p += 4 * SL * 2;               // 7.68 MB
    __half* Tns      = (__half*)p;     // 7.68 MB -> total ~33 MB
    __half* Y1s      = Ys;             // reused after fused_attn

    const int edge_blocks = (EE + 255) / 256;
    const int nw_blocks   = (NN + 3) / 4;
    const int sl_blocks   = NN;        // 15000 node-groups x 4 intents (pinned)

    // CSR build
    hipMemsetAsync(deg0, 0, NN * sizeof(int), stream);
    hipMemsetAsync(cursor, 0, NN * sizeof(int), stream);
    edge_count<<<edge_blocks, 256, 0, stream>>>(eh, deg0);
    scan_offsets<<<1, 1024, 0, stream>>>(deg0, offsets);
    edge_scatter<<<edge_blocks, 256, 0, stream>>>(eh, et, offsets, cursor, csr_tail);

    // iter 0: sliced tables + fused Z1/attention
    prep0s<<<nw_blocks, 256, 0, stream>>>(Gu, Gi, deg0, Tns, Ys);
    fused_attn<<<sl_blocks, 256, 0, stream>>>(offsets, csr_tail, Ys, Tns, v);

    // softmax + dcol1 + Y1s in one pass
    sm_dcol_y1<<<nw_blocks, 256, 0, stream>>>(offsets, v, scores, dcol1, Gu, Gi, Y1s);

    // iter 1 propagate + finalize
    outk<<<sl_blocks, 256, 0, stream>>>(offsets, csr_tail, Y1s, scores, dcol1, Gu, Gi, out);
}

// Round 11
// 343.433 us; speedup vs baseline: 1.7467x; 1.3190x over previous
//
#include <hip/hip_runtime.h>
#include <hip/hip_fp16.h>

// DGCF single-layer, 2 routing iters (MI355X). fp32 in / fp32 out.
// R10 post-mortem: single-block scan_offsets was 114us (occ 0.16%) -- 25% of
// runtime. R11: classic 3-kernel parallel scan (coalesced block scan ->
// block-sum scan -> in-place add; offsets[NN]=EE is constant). Everything
// else identical to R10 (passing, 453us):
//  - 16 edges x 4 ch lane map, coalesced tail/score loads, packed __hfma2
//  - slice-major [intent][N][16] fp16 tables, [intent][E] edge streams
//  - blockIdx%8 XCD pinning for L2-resident slices

#define NUSERS 30000
#define NN     60000
#define EE     800000
#define SL     ((size_t)NN * 16)   // elements per intent slice
#define SCAN_B ((NN + 255) / 256)  // 235 scan blocks

__device__ __forceinline__ float getX(const float* __restrict__ Gu,
                                      const float* __restrict__ Gi,
                                      int n, int c) {
    return (n < NUSERS) ? Gu[n * 64 + c] : Gi[(n - NUSERS) * 64 + c];
}

__device__ __forceinline__ int clampN(int n) {
    return ((unsigned)n < (unsigned)NN) ? n : 0;
}

__device__ __forceinline__ __half2 shfl_xor_h2(__half2 x, int m) {
    int xi = __builtin_bit_cast(int, x);
    xi = __shfl_xor(xi, m, 64);
    return __builtin_bit_cast(__half2, xi);
}

// Pinned-block index decode: blockIdx b -> intent i (XCD pair), node n.
__device__ __forceinline__ int pinnedNode(int b, int tid, int* i) {
    int xcd = b & 7;
    *i = xcd >> 1;
    int g = (b >> 3) * 2 + (xcd & 1);          // node-group in [0,15000)
    return g * 4 + (tid >> 6);
}

// ---- CSR build ----

__global__ void edge_count(const int* __restrict__ eh, int* __restrict__ deg0) {
    int e = blockIdx.x * blockDim.x + threadIdx.x;
    if (e >= EE) return;
    atomicAdd(&deg0[clampN(eh[e])], 1);
}

// In-block exclusive scan of 256 ints (4 waves), coalesced. Writes the
// per-element exclusive prefix into offsets[] and the block total to bsum.
__global__ void scan_local(const int* __restrict__ deg0, int* __restrict__ offsets,
                           int* __restrict__ bsum) {
    int gid = blockIdx.x * 256 + threadIdx.x;
    int lane = threadIdx.x & 63, w = threadIdx.x >> 6;
    int vdeg = (gid < NN) ? deg0[gid] : 0;
    int x = vdeg;
    #pragma unroll
    for (int d = 1; d < 64; d <<= 1) {
        int y = __shfl_up(x, d, 64);
        if (lane >= d) x += y;
    }
    __shared__ int wsum[4];
    if (lane == 63) wsum[w] = x;
    __syncthreads();
    int wpre = 0;
    #pragma unroll
    for (int j = 0; j < 4; ++j) wpre += (j < w) ? wsum[j] : 0;
    int incl = x + wpre;
    if (gid < NN) offsets[gid] = incl - vdeg;
    if (threadIdx.x == 255) bsum[blockIdx.x] = incl;
}

// One block: exclusive scan of the SCAN_B block sums, in place.
__global__ void scan_bsums(int* __restrict__ bsum) {
    int tid = threadIdx.x;                 // 256 threads, SCAN_B=235 < 256
    int lane = tid & 63, w = tid >> 6;
    int v = (tid < SCAN_B) ? bsum[tid] : 0;
    int x = v;
    #pragma unroll
    for (int d = 1; d < 64; d <<= 1) {
        int y = __shfl_up(x, d, 64);
        if (lane >= d) x += y;
    }
    __shared__ int wsum[4];
    if (lane == 63) wsum[w] = x;
    __syncthreads();
    int wpre = 0;
    #pragma unroll
    for (int j = 0; j < 4; ++j) wpre += (j < w) ? wsum[j] : 0;
    if (tid < SCAN_B) bsum[tid] = x + wpre - v;   // exclusive
}

// Add block prefix in place; offsets[NN] = EE (total edge count, exact).
__global__ void scan_add(int* __restrict__ offsets, const int* __restrict__ bsum) {
    int gid = blockIdx.x * 256 + threadIdx.x;
    if (gid < NN) offsets[gid] += bsum[blockIdx.x];
    if (gid == 0) offsets[NN] = EE;
}

__global__ void edge_scatter(const int* __restrict__ eh, const int* __restrict__ et,
                             const int* __restrict__ offsets, int* __restrict__ cursor,
                             int* __restrict__ csr_tail) {
    int e = blockIdx.x * blockDim.x + threadIdx.x;
    if (e >= EE) return;
    int h = clampN(eh[e]);
    int slot = offsets[h] + atomicAdd(&cursor[h], 1);
    if (slot < EE) csr_tail[slot] = clampN(et[e]);
}

// ---- node-side precompute ----

// Wave/node: Tns[i][n][ch] = tanh(x/|x|_i), Ys[i][n][ch] = dcol0*x  (fp16)
__global__ void prep0s(const float* __restrict__ Gu, const float* __restrict__ Gi,
                       const int* __restrict__ deg0,
                       __half* __restrict__ Tns, __half* __restrict__ Ys) {
    int n = blockIdx.x * 4 + (threadIdx.x >> 6);
    if (n >= NN) return;
    int lane = threadIdx.x & 63;
    int i = lane >> 4, ch = lane & 15;
    float x = getX(Gu, Gi, n, lane);
    float sx = x * x;
    #pragma unroll
    for (int m = 1; m < 16; m <<= 1) sx += __shfl_xor(sx, m, 64);
    float invx = rsqrtf(fmaxf(sx, 1e-12f));
    size_t a = (size_t)i * SL + (size_t)n * 16 + ch;
    Tns[a] = __float2half(tanhf(x * invx));
    float d0 = rsqrtf(fmaxf(0.25f * (float)deg0[n], 1e-30f));
    Ys[a] = __float2half(d0 * x);
}

// ---- fused pinned pass: Z1 accumulate + l2norm + attention dots ----
// Wave = (node, intent); lane = (edge slot e4 = lane>>2) x (ch-quad cp = lane&3).
__global__ void fused_attn(const int* __restrict__ offsets, const int* __restrict__ csr_tail,
                           const __half* __restrict__ Ys, const __half* __restrict__ Tns,
                           __half* __restrict__ v) {
    int i;
    int n = pinnedNode(blockIdx.x, threadIdx.x, &i);
    int lane = threadIdx.x & 63;
    int e4 = lane >> 2, cp = lane & 3;
    int s0 = offsets[n], s1 = offsets[n + 1];
    const __half* Yi = Ys + (size_t)i * SL;
    const __half* Ti = Tns + (size_t)i * SL;
    const __half2 h2z = __floats2half2_rn(0.f, 0.f);

    // phase 1: Z accumulate, 4 channels (2 half2) per lane, 16 edges/iter.
    __half2 z0 = h2z, z1 = h2z;
    for (int base = s0; base < s1; base += 16) {
        int kk = base + e4;
        bool act = kk < s1;
        int t = act ? csr_tail[kk] : 0;
        const __half2* row = (const __half2*)(Yi + (size_t)t * 16 + cp * 4);
        __half2 a = row[0], b = row[1];
        z0 = __hadd2(z0, act ? a : h2z);
        z1 = __hadd2(z1, act ? b : h2z);
    }
    // reduce across the 16 edge slots (xor lane bits 2..5); all lanes active
    #pragma unroll
    for (int m = 4; m < 64; m <<= 1) {
        z0 = __hadd2(z0, shfl_xor_h2(z0, m));
        z1 = __hadd2(z1, shfl_xor_h2(z1, m));
    }
    // per-intent sumsq: own 4 ch + xor 1,2 across ch-quads
    float2 f0 = __half22float2(z0), f1 = __half22float2(z1);
    float ss = f0.x * f0.x + f0.y * f0.y + f1.x * f1.x + f1.y * f1.y;
    ss += __shfl_xor(ss, 1, 64);
    ss += __shfl_xor(ss, 2, 64);
    float inv = rsqrtf(fmaxf(ss, 1e-12f));
    __half2 zn0 = __floats2half2_rn(f0.x * inv, f0.y * inv);
    __half2 zn1 = __floats2half2_rn(f1.x * inv, f1.y * inv);

    // phase 2: dot(zn, Tn[t]) per edge -> v[i*E + k]
    __half* vi = v + (size_t)i * EE;
    for (int base = s0; base < s1; base += 16) {
        int kk = base + e4;
        bool act = kk < s1;
        int t = act ? csr_tail[kk] : 0;
        const __half2* row = (const __half2*)(Ti + (size_t)t * 16 + cp * 4);
        __half2 d2 = __hmul2(zn0, row[0]);
        d2 = __hfma2(zn1, row[1], d2);
        float2 df = __half22float2(d2);
        float p = df.x + df.y;
        p += __shfl_xor(p, 1, 64);
        p += __shfl_xor(p, 2, 64);
        if (act && cp == 0) vi[kk] = __float2half(p);
    }
}

// ---- fused softmax + deg1 + dcol1 + Y1s build (wave per node) ----
__global__ void sm_dcol_y1(const int* __restrict__ offsets, const __half* __restrict__ v,
                           __half* __restrict__ scores, float* __restrict__ dcol1,
                           const float* __restrict__ Gu, const float* __restrict__ Gi,
                           __half* __restrict__ Y1s) {
    int n = blockIdx.x * 4 + (threadIdx.x >> 6);
    if (n >= NN) return;
    int lane = threadIdx.x & 63;
    int s0 = offsets[n], s1 = offsets[n + 1];
    float sum0 = 0.f, sum1 = 0.f, sum2 = 0.f, sum3 = 0.f;
    for (int k = s0 + lane; k < s1; k += 64) {
        float v0 = __half2float(v[k]);
        float v1 = __half2float(v[EE + k]);
        float v2 = __half2float(v[2 * EE + k]);
        float v3 = __half2float(v[3 * EE + k]);
        float mx = fmaxf(fmaxf(v0, v1), fmaxf(v2, v3));
        float e0 = __expf(v0 - mx), e1 = __expf(v1 - mx);
        float e2 = __expf(v2 - mx), e3 = __expf(v3 - mx);
        float inv = 1.f / (e0 + e1 + e2 + e3);
        e0 *= inv; e1 *= inv; e2 *= inv; e3 *= inv;
        scores[k]          = __float2half(e0);
        scores[EE + k]     = __float2half(e1);
        scores[2 * EE + k] = __float2half(e2);
        scores[3 * EE + k] = __float2half(e3);
        sum0 += e0; sum1 += e1; sum2 += e2; sum3 += e3;
    }
    #pragma unroll
    for (int m = 1; m < 64; m <<= 1) {
        sum0 += __shfl_xor(sum0, m, 64);
        sum1 += __shfl_xor(sum1, m, 64);
        sum2 += __shfl_xor(sum2, m, 64);
        sum3 += __shfl_xor(sum3, m, 64);
    }
    int i = lane >> 4, ch = lane & 15;
    float dsel = (i == 0) ? sum0 : (i == 1) ? sum1 : (i == 2) ? sum2 : sum3;
    float d = rsqrtf(fmaxf(dsel, 1e-30f));
    if (lane < 4) {
        float ds = (lane == 0) ? sum0 : (lane == 1) ? sum1 : (lane == 2) ? sum2 : sum3;
        dcol1[n * 4 + lane] = rsqrtf(fmaxf(ds, 1e-30f));
    }
    float x = getX(Gu, Gi, n, lane);
    Y1s[(size_t)i * SL + (size_t)n * 16 + ch] = __float2half(d * x);
}

// ---- pinned output pass: Z2 gather + finalize ----
// Lane = (edge slot e4) x (ch-quad cp); fp32 per-lane accum; float4 stores.
__global__ void outk(const int* __restrict__ offsets, const int* __restrict__ csr_tail,
                     const __half* __restrict__ Y1s, const __half* __restrict__ scores,
                     const float* __restrict__ dcol1,
                     const float* __restrict__ Gu, const float* __restrict__ Gi,
                     float* __restrict__ out) {
    int i;
    int n = pinnedNode(blockIdx.x, threadIdx.x, &i);
    int lane = threadIdx.x & 63;
    int e4 = lane >> 2, cp = lane & 3;
    int s0 = offsets[n], s1 = offsets[n + 1];
    const __half* Yi = Y1s + (size_t)i * SL;
    const __half* si = scores + (size_t)i * EE;

    float a0 = 0.f, a1 = 0.f, a2 = 0.f, a3 = 0.f;
    for (int base = s0; base < s1; base += 16) {
        int kk = base + e4;
        bool act = kk < s1;
        int t = act ? csr_tail[kk] : 0;
        float s = act ? __half2float(si[kk]) : 0.f;
        const __half2* row = (const __half2*)(Yi + (size_t)t * 16 + cp * 4);
        float2 r0 = __half22float2(row[0]), r1 = __half22float2(row[1]);
        a0 += s * r0.x; a1 += s * r0.y; a2 += s * r1.x; a3 += s * r1.y;
    }
    #pragma unroll
    for (int m = 4; m < 64; m <<= 1) {
        a0 += __shfl_xor(a0, m, 64);
        a1 += __shfl_xor(a1, m, 64);
        a2 += __shfl_xor(a2, m, 64);
        a3 += __shfl_xor(a3, m, 64);
    }
    if (e4 == 0) {
        int c = i * 16 + cp * 4;
        const float* xr = (n < NUSERS) ? (Gu + n * 64 + c) : (Gi + (n - NUSERS) * 64 + c);
        float4 x4 = *(const float4*)xr;
        float d = dcol1[n * 4 + i];
        float4 o;
        o.x = 0.5f * (x4.x + d * a0);
        o.y = 0.5f * (x4.y + d * a1);
        o.z = 0.5f * (x4.z + d * a2);
        o.w = 0.5f * (x4.w + d * a3);
        *(float4*)(out + (size_t)n * 64 + c) = o;
    }
}

// ---- launch ----

extern "C" void kernel_launch(void* const* d_in, const int* in_sizes, int n_in,
                              void* d_out, int out_size, void* d_ws, size_t ws_size,
                              hipStream_t stream) {
    const float* Gu = (const float*)d_in[0];
    const float* Gi = (const float*)d_in[1];
    const int* eh = (const int*)d_in[2];
    const int* et = (const int*)d_in[3];
    float* out = (float*)d_out;

    char* p = (char*)d_ws;
    __half* v        = (__half*)p;     p += (size_t)EE * 4 * 2;       // 6.4 MB
    __half* scores   = (__half*)p;     p += (size_t)EE * 4 * 2;       // 6.4 MB
    int*    csr_tail = (int*)p;        p += (size_t)EE * 4;           // 3.2 MB
    int*    offsets  = (int*)p;        p += ((size_t)(NN + 1) * 4 + 15) / 16 * 16;
    int*    deg0     = (int*)p;        p += (size_t)NN * 4;
    int*    cursor   = (int*)p;        p += (size_t)NN * 4;
    int*    bsum     = (int*)p;        p += ((size_t)SCAN_B * 4 + 15) / 16 * 16;
    float*  dcol1    = (float*)p;      p += (size_t)NN * 4 * 4;
    __half* Ys       = (__half*)p;     p += 4 * SL * 2;               // 7.68 MB
    __half* Tns      = (__half*)p;     // 7.68 MB -> total ~33 MB
    __half* Y1s      = Ys;             // reused after fused_attn

    const int edge_blocks = (EE + 255) / 256;
    const int nw_blocks   = (NN + 3) / 4;
    const int sl_blocks   = NN;        // 15000 node-groups x 4 intents (pinned)

    // CSR build (parallel scan)
    hipMemsetAsync(deg0, 0, NN * sizeof(int), stream);
    hipMemsetAsync(cursor, 0, NN * sizeof(int), stream);
    edge_count<<<edge_blocks, 256, 0, stream>>>(eh, deg0);
    scan_local<<<SCAN_B, 256, 0, stream>>>(deg0, offsets, bsum);
    scan_bsums<<<1, 256, 0, stream>>>(bsum);
    scan_add<<<SCAN_B, 256, 0, stream>>>(offsets, bsum);
    edge_scatter<<<edge_blocks, 256, 0, stream>>>(eh, et, offsets, cursor, csr_tail);

    // iter 0: sliced tables + fused Z1/attention
    prep0s<<<nw_blocks, 256, 0, stream>>>(Gu, Gi, deg0, Tns, Ys);
    fused_attn<<<sl_blocks, 256, 0, stream>>>(offsets, csr_tail, Ys, Tns, v);

    // softmax + dcol1 + Y1s in one pass
    sm_dcol_y1<<<nw_blocks, 256, 0, stream>>>(offsets, v, scores, dcol1, Gu, Gi, Y1s);

    // iter 1 propagate + finalize
    outk<<<sl_blocks, 256, 0, stream>>>(offsets, csr_tail, Y1s, scores, dcol1, Gu, Gi, out);
}

// Round 12
// 315.738 us; speedup vs baseline: 1.8999x; 1.0877x over previous
//
#include <hip/hip_runtime.h>
#include <hip/hip_fp16.h>

// DGCF single-layer, 2 routing iters (MI355X). fp32 in / fp32 out.
// R11 post-mortem: fused_attn 87us (VALU 50%, FETCH 44MB) -- two random lines
// per edge (Y then T) + csr_tail read twice. R12:
//  - interleaved YT rows [intent][node][cp: Y4|T4] (64B/row): ONE dwordx4 per
//    lane fetches Y+T; deg<=32 fast path (covers ~100% of nodes, wave-uniform
//    branch) caches T in regs -> phase 2 has NO memory ops
//  - zero row at node index NN kills accumulate cndmasks
//  - scan_local zeroes cursor; scan_bsums+scan_add merged (11 -> 9 dispatches)
// Unchanged: 16 edges x 4 ch lane map, [intent][E] edge streams, blockIdx%8
// XCD pinning, sm_dcol_y1, outk (Y1s aliases YT memory after last YT read).

#define NUSERS 30000
#define NN     60000
#define EE     800000
#define SL     ((size_t)NN * 16)        // Y1s slice elements
#define SLY    ((size_t)(NN + 1) * 32)  // YT slice elements (+ zero row)
#define SCAN_B ((NN + 255) / 256)       // 235 scan blocks

__device__ __forceinline__ float getX(const float* __restrict__ Gu,
                                      const float* __restrict__ Gi,
                                      int n, int c) {
    return (n < NUSERS) ? Gu[n * 64 + c] : Gi[(n - NUSERS) * 64 + c];
}

__device__ __forceinline__ int clampN(int n) {
    return ((unsigned)n < (unsigned)NN) ? n : 0;
}

__device__ __forceinline__ __half2 shfl_xor_h2(__half2 x, int m) {
    int xi = __builtin_bit_cast(int, x);
    xi = __shfl_xor(xi, m, 64);
    return __builtin_bit_cast(__half2, xi);
}

// Pinned-block index decode: blockIdx b -> intent i (XCD pair), node n.
__device__ __forceinline__ int pinnedNode(int b, int tid, int* i) {
    int xcd = b & 7;
    *i = xcd >> 1;
    int g = (b >> 3) * 2 + (xcd & 1);          // node-group in [0,15000)
    return g * 4 + (tid >> 6);
}

// ---- CSR build ----

__global__ void edge_count(const int* __restrict__ eh, int* __restrict__ deg0) {
    int e = blockIdx.x * blockDim.x + threadIdx.x;
    if (e >= EE) return;
    atomicAdd(&deg0[clampN(eh[e])], 1);
}

// In-block exclusive scan of 256 ints; also zeroes cursor for edge_scatter.
__global__ void scan_local(const int* __restrict__ deg0, int* __restrict__ offsets,
                           int* __restrict__ bsum, int* __restrict__ cursor) {
    int gid = blockIdx.x * 256 + threadIdx.x;
    int lane = threadIdx.x & 63, w = threadIdx.x >> 6;
    int vdeg = (gid < NN) ? deg0[gid] : 0;
    if (gid < NN) cursor[gid] = 0;
    int x = vdeg;
    #pragma unroll
    for (int d = 1; d < 64; d <<= 1) {
        int y = __shfl_up(x, d, 64);
        if (lane >= d) x += y;
    }
    __shared__ int wsum[4];
    if (lane == 63) wsum[w] = x;
    __syncthreads();
    int wpre = 0;
    #pragma unroll
    for (int j = 0; j < 4; ++j) wpre += (j < w) ? wsum[j] : 0;
    int incl = x + wpre;
    if (gid < NN) offsets[gid] = incl - vdeg;
    if (threadIdx.x == 255) bsum[blockIdx.x] = incl;
}

// Each block re-scans the 235 block sums (cheap) and adds its own prefix.
__global__ void scan_add2(int* __restrict__ offsets, const int* __restrict__ bsum) {
    int tid = threadIdx.x, lane = tid & 63, w = tid >> 6;
    int vv = (tid < SCAN_B) ? bsum[tid] : 0;
    int x = vv;
    #pragma unroll
    for (int d = 1; d < 64; d <<= 1) {
        int y = __shfl_up(x, d, 64);
        if (lane >= d) x += y;
    }
    __shared__ int wsum[4];
    __shared__ int bpre;
    if (lane == 63) wsum[w] = x;
    __syncthreads();
    int wpre = 0;
    #pragma unroll
    for (int j = 0; j < 4; ++j) wpre += (j < w) ? wsum[j] : 0;
    if (tid == blockIdx.x) bpre = x + wpre - vv;   // exclusive prefix of this block
    __syncthreads();
    int gid = blockIdx.x * 256 + tid;
    if (gid < NN) offsets[gid] += bpre;
    if (gid == 0) offsets[NN] = EE;
}

__global__ void edge_scatter(const int* __restrict__ eh, const int* __restrict__ et,
                             const int* __restrict__ offsets, int* __restrict__ cursor,
                             int* __restrict__ csr_tail) {
    int e = blockIdx.x * blockDim.x + threadIdx.x;
    if (e >= EE) return;
    int h = clampN(eh[e]);
    int slot = offsets[h] + atomicAdd(&cursor[h], 1);
    if (slot < EE) csr_tail[slot] = clampN(et[e]);
}

// ---- node-side precompute: YT[i][n][cp] = {Y quad, T quad}, + zero row n==NN ----

__global__ void prep0s(const float* __restrict__ Gu, const float* __restrict__ Gi,
                       const int* __restrict__ deg0, __half* __restrict__ YT) {
    int n = blockIdx.x * 4 + (threadIdx.x >> 6);
    if (n > NN) return;
    int lane = threadIdx.x & 63;
    int i = lane >> 4, ch = lane & 15;
    float x = (n < NN) ? getX(Gu, Gi, n, lane) : 0.f;
    float sx = x * x;
    #pragma unroll
    for (int m = 1; m < 16; m <<= 1) sx += __shfl_xor(sx, m, 64);
    float invx = rsqrtf(fmaxf(sx, 1e-12f));
    float d0 = rsqrtf(fmaxf(0.25f * (float)((n < NN) ? deg0[n] : 1), 1e-30f));
    size_t a = (size_t)i * SLY + (size_t)n * 32 + (size_t)(ch >> 2) * 8 + (ch & 3);
    YT[a]     = __float2half(d0 * x);          // Y quad slot
    YT[a + 4] = __float2half(tanhf(x * invx)); // T quad slot
}

// ---- fused pinned pass: Z1 accumulate + l2norm + attention dots ----
// Wave = (node, intent); lane = (edge slot e4 = lane>>2) x (ch-quad cp = lane&3).
// deg<=32 fast path: ONE dwordx4/lane/edge fetches Y+T; T cached in regs.
__global__ void fused_attn(const int* __restrict__ offsets, const int* __restrict__ csr_tail,
                           const __half* __restrict__ YT, __half* __restrict__ v) {
    int i;
    int n = pinnedNode(blockIdx.x, threadIdx.x, &i);
    int lane = threadIdx.x & 63;
    int e4 = lane >> 2, cp = lane & 3;
    int s0 = offsets[n], s1 = offsets[n + 1];
    int deg = s1 - s0;
    const __half* Yi = YT + (size_t)i * SLY;
    const __half2 h2z = __floats2half2_rn(0.f, 0.f);

    __half2 z0 = h2z, z1 = h2z;
    __half2 tA0 = h2z, tA1 = h2z, tB0 = h2z, tB1 = h2z;
    bool actA = false, actB = false;
    bool fast = (deg <= 32);

    if (fast) {
        int kkA = s0 + e4; actA = kkA < s1;
        int tA = actA ? csr_tail[kkA] : NN;                 // NN = zero row
        const __half2* rA = (const __half2*)(Yi + (size_t)tA * 32 + cp * 8);
        z0 = rA[0]; z1 = rA[1]; tA0 = rA[2]; tA1 = rA[3];
        if (deg > 16) {
            int kkB = s0 + 16 + e4; actB = kkB < s1;
            int tB = actB ? csr_tail[kkB] : NN;
            const __half2* rB = (const __half2*)(Yi + (size_t)tB * 32 + cp * 8);
            z0 = __hadd2(z0, rB[0]); z1 = __hadd2(z1, rB[1]);
            tB0 = rB[2]; tB1 = rB[3];
        }
    } else {
        for (int base = s0; base < s1; base += 16) {
            int kk = base + e4;
            int t = (kk < s1) ? csr_tail[kk] : NN;
            const __half2* r = (const __half2*)(Yi + (size_t)t * 32 + cp * 8);
            z0 = __hadd2(z0, r[0]); z1 = __hadd2(z1, r[1]);
        }
    }
    // reduce across 16 edge slots; all lanes active
    #pragma unroll
    for (int m = 4; m < 64; m <<= 1) {
        z0 = __hadd2(z0, shfl_xor_h2(z0, m));
        z1 = __hadd2(z1, shfl_xor_h2(z1, m));
    }
    float2 f0 = __half22float2(z0), f1 = __half22float2(z1);
    float ss = f0.x * f0.x + f0.y * f0.y + f1.x * f1.x + f1.y * f1.y;
    ss += __shfl_xor(ss, 1, 64);
    ss += __shfl_xor(ss, 2, 64);
    float inv = rsqrtf(fmaxf(ss, 1e-12f));
    __half2 zn0 = __floats2half2_rn(f0.x * inv, f0.y * inv);
    __half2 zn1 = __floats2half2_rn(f1.x * inv, f1.y * inv);

    __half* vi = v + (size_t)i * EE;
    if (fast) {
        __half2 d2 = __hmul2(zn0, tA0); d2 = __hfma2(zn1, tA1, d2);
        float2 df = __half22float2(d2);
        float p = df.x + df.y;
        p += __shfl_xor(p, 1, 64);
        p += __shfl_xor(p, 2, 64);
        if (actA && cp == 0) vi[s0 + e4] = __float2half(p);
        if (deg > 16) {
            __half2 e2 = __hmul2(zn0, tB0); e2 = __hfma2(zn1, tB1, e2);
            float2 ef = __half22float2(e2);
            float q = ef.x + ef.y;
            q += __shfl_xor(q, 1, 64);
            q += __shfl_xor(q, 2, 64);
            if (actB && cp == 0) vi[s0 + 16 + e4] = __float2half(q);
        }
    } else {
        for (int base = s0; base < s1; base += 16) {
            int kk = base + e4;
            bool act = kk < s1;
            int t = act ? csr_tail[kk] : NN;
            const __half2* r = (const __half2*)(Yi + (size_t)t * 32 + cp * 8 + 4);
            __half2 d2 = __hmul2(zn0, r[0]); d2 = __hfma2(zn1, r[1], d2);
            float2 df = __half22float2(d2);
            float p = df.x + df.y;
            p += __shfl_xor(p, 1, 64);
            p += __shfl_xor(p, 2, 64);
            if (act && cp == 0) vi[kk] = __float2half(p);
        }
    }
}

// ---- fused softmax + deg1 + dcol1 + Y1s build (wave per node) ----
__global__ void sm_dcol_y1(const int* __restrict__ offsets, const __half* __restrict__ v,
                           __half* __restrict__ scores, float* __restrict__ dcol1,
                           const float* __restrict__ Gu, const float* __restrict__ Gi,
                           __half* __restrict__ Y1s) {
    int n = blockIdx.x * 4 + (threadIdx.x >> 6);
    if (n >= NN) return;
    int lane = threadIdx.x & 63;
    int s0 = offsets[n], s1 = offsets[n + 1];
    float sum0 = 0.f, sum1 = 0.f, sum2 = 0.f, sum3 = 0.f;
    for (int k = s0 + lane; k < s1; k += 64) {
        float v0 = __half2float(v[k]);
        float v1 = __half2float(v[EE + k]);
        float v2 = __half2float(v[2 * EE + k]);
        float v3 = __half2float(v[3 * EE + k]);
        float mx = fmaxf(fmaxf(v0, v1), fmaxf(v2, v3));
        float e0 = __expf(v0 - mx), e1 = __expf(v1 - mx);
        float e2 = __expf(v2 - mx), e3 = __expf(v3 - mx);
        float inv = 1.f / (e0 + e1 + e2 + e3);
        e0 *= inv; e1 *= inv; e2 *= inv; e3 *= inv;
        scores[k]          = __float2half(e0);
        scores[EE + k]     = __float2half(e1);
        scores[2 * EE + k] = __float2half(e2);
        scores[3 * EE + k] = __float2half(e3);
        sum0 += e0; sum1 += e1; sum2 += e2; sum3 += e3;
    }
    #pragma unroll
    for (int m = 1; m < 64; m <<= 1) {
        sum0 += __shfl_xor(sum0, m, 64);
        sum1 += __shfl_xor(sum1, m, 64);
        sum2 += __shfl_xor(sum2, m, 64);
        sum3 += __shfl_xor(sum3, m, 64);
    }
    int i = lane >> 4, ch = lane & 15;
    float dsel = (i == 0) ? sum0 : (i == 1) ? sum1 : (i == 2) ? sum2 : sum3;
    float d = rsqrtf(fmaxf(dsel, 1e-30f));
    if (lane < 4) {
        float ds = (lane == 0) ? sum0 : (lane == 1) ? sum1 : (lane == 2) ? sum2 : sum3;
        dcol1[n * 4 + lane] = rsqrtf(fmaxf(ds, 1e-30f));
    }
    float x = getX(Gu, Gi, n, lane);
    Y1s[(size_t)i * SL + (size_t)n * 16 + ch] = __float2half(d * x);
}

// ---- pinned output pass: Z2 gather + finalize ----
__global__ void outk(const int* __restrict__ offsets, const int* __restrict__ csr_tail,
                     const __half* __restrict__ Y1s, const __half* __restrict__ scores,
                     const float* __restrict__ dcol1,
                     const float* __restrict__ Gu, const float* __restrict__ Gi,
                     float* __restrict__ out) {
    int i;
    int n = pinnedNode(blockIdx.x, threadIdx.x, &i);
    int lane = threadIdx.x & 63;
    int e4 = lane >> 2, cp = lane & 3;
    int s0 = offsets[n], s1 = offsets[n + 1];
    const __half* Yi = Y1s + (size_t)i * SL;
    const __half* si = scores + (size_t)i * EE;

    float a0 = 0.f, a1 = 0.f, a2 = 0.f, a3 = 0.f;
    for (int base = s0; base < s1; base += 16) {
        int kk = base + e4;
        bool act = kk < s1;
        int t = act ? csr_tail[kk] : 0;
        float s = act ? __half2float(si[kk]) : 0.f;
        const __half2* row = (const __half2*)(Yi + (size_t)t * 16 + cp * 4);
        float2 r0 = __half22float2(row[0]), r1 = __half22float2(row[1]);
        a0 += s * r0.x; a1 += s * r0.y; a2 += s * r1.x; a3 += s * r1.y;
    }
    #pragma unroll
    for (int m = 4; m < 64; m <<= 1) {
        a0 += __shfl_xor(a0, m, 64);
        a1 += __shfl_xor(a1, m, 64);
        a2 += __shfl_xor(a2, m, 64);
        a3 += __shfl_xor(a3, m, 64);
    }
    if (e4 == 0) {
        int c = i * 16 + cp * 4;
        const float* xr = (n < NUSERS) ? (Gu + n * 64 + c) : (Gi + (n - NUSERS) * 64 + c);
        float4 x4 = *(const float4*)xr;
        float d = dcol1[n * 4 + i];
        float4 o;
        o.x = 0.5f * (x4.x + d * a0);
        o.y = 0.5f * (x4.y + d * a1);
        o.z = 0.5f * (x4.z + d * a2);
        o.w = 0.5f * (x4.w + d * a3);
        *(float4*)(out + (size_t)n * 64 + c) = o;
    }
}

// ---- launch ----

extern "C" void kernel_launch(void* const* d_in, const int* in_sizes, int n_in,
                              void* d_out, int out_size, void* d_ws, size_t ws_size,
                              hipStream_t stream) {
    const float* Gu = (const float*)d_in[0];
    const float* Gi = (const float*)d_in[1];
    const int* eh = (const int*)d_in[2];
    const int* et = (const int*)d_in[3];
    float* out = (float*)d_out;

    char* p = (char*)d_ws;
    __half* v        = (__half*)p;     p += (size_t)EE * 4 * 2;       // 6.4 MB
    __half* scores   = (__half*)p;     p += (size_t)EE * 4 * 2;       // 6.4 MB
    int*    csr_tail = (int*)p;        p += (size_t)EE * 4;           // 3.2 MB
    int*    offsets  = (int*)p;        p += ((size_t)(NN + 1) * 4 + 15) / 16 * 16;
    int*    deg0     = (int*)p;        p += (size_t)NN * 4;
    int*    cursor   = (int*)p;        p += (size_t)NN * 4;
    int*    bsum     = (int*)p;        p += ((size_t)SCAN_B * 4 + 15) / 16 * 16;
    float*  dcol1    = (float*)p;      p += (size_t)NN * 4 * 4;
    __half* YT       = (__half*)p;     // 4*SLY*2 = 15.36 MB -> total ~33 MB
    __half* Y1s      = YT;             // aliases YT (YT last read in fused_attn)

    const int edge_blocks = (EE + 255) / 256;
    const int nw_blocks   = (NN + 3) / 4;
    const int nw1_blocks  = (NN + 1 + 3) / 4;   // covers zero row n==NN
    const int sl_blocks   = NN;        // 15000 node-groups x 4 intents (pinned)

    // CSR build
    hipMemsetAsync(deg0, 0, NN * sizeof(int), stream);
    edge_count<<<edge_blocks, 256, 0, stream>>>(eh, deg0);
    scan_local<<<SCAN_B, 256, 0, stream>>>(deg0, offsets, bsum, cursor);
    scan_add2<<<SCAN_B, 256, 0, stream>>>(offsets, bsum);
    edge_scatter<<<edge_blocks, 256, 0, stream>>>(eh, et, offsets, cursor, csr_tail);

    // iter 0: interleaved YT table + fused Z1/attention
    prep0s<<<nw1_blocks, 256, 0, stream>>>(Gu, Gi, deg0, YT);
    fused_attn<<<sl_blocks, 256, 0, stream>>>(offsets, csr_tail, YT, v);

    // softmax + dcol1 + Y1s in one pass
    sm_dcol_y1<<<nw_blocks, 256, 0, stream>>>(offsets, v, scores, dcol1, Gu, Gi, Y1s);

    // iter 1 propagate + finalize
    outk<<<sl_blocks, 256, 0, stream>>>(offsets, csr_tail, Y1s, scores, dcol1, Gu, Gi, out);
}

// Round 13
// 314.529 us; speedup vs baseline: 1.9072x; 1.0038x over previous
//
#include <hip/hip_runtime.h>
#include <hip/hip_fp16.h>

// DGCF single-layer, 2 routing iters (MI355X). fp32 in / fp32 out.
// R12 post-mortem: outk now top (80us, VALU 44%, ~39us pure issue across 240K
// waves). R13:
//  - outk: deg<=32 wave-uniform fast path (1-2 unrolled 16-edge bursts, no
//    loop bookkeeping; inactive slots s=0) + half2-packed cross-slot reduce
//    (16 fp32 shuffles -> 8 hadd2)
//  - edge_count/edge_scatter: int4-vectorized (4 edges/thread)
// Unchanged from R12 (passing, 316us): YT interleaved table, fused_attn fast
// path, parallel scan, sm_dcol_y1, [intent][E] streams, XCD pinning.

#define NUSERS 30000
#define NN     60000
#define EE     800000
#define SL     ((size_t)NN * 16)        // Y1s slice elements
#define SLY    ((size_t)(NN + 1) * 32)  // YT slice elements (+ zero row)
#define SCAN_B ((NN + 255) / 256)       // 235 scan blocks

__device__ __forceinline__ float getX(const float* __restrict__ Gu,
                                      const float* __restrict__ Gi,
                                      int n, int c) {
    return (n < NUSERS) ? Gu[n * 64 + c] : Gi[(n - NUSERS) * 64 + c];
}

__device__ __forceinline__ int clampN(int n) {
    return ((unsigned)n < (unsigned)NN) ? n : 0;
}

__device__ __forceinline__ __half2 shfl_xor_h2(__half2 x, int m) {
    int xi = __builtin_bit_cast(int, x);
    xi = __shfl_xor(xi, m, 64);
    return __builtin_bit_cast(__half2, xi);
}

// Pinned-block index decode: blockIdx b -> intent i (XCD pair), node n.
__device__ __forceinline__ int pinnedNode(int b, int tid, int* i) {
    int xcd = b & 7;
    *i = xcd >> 1;
    int g = (b >> 3) * 2 + (xcd & 1);          // node-group in [0,15000)
    return g * 4 + (tid >> 6);
}

// ---- CSR build ----

__global__ void edge_count(const int* __restrict__ eh, int* __restrict__ deg0) {
    int e4 = (blockIdx.x * blockDim.x + threadIdx.x) * 4;
    if (e4 >= EE) return;
    int4 h = *(const int4*)(eh + e4);
    atomicAdd(&deg0[clampN(h.x)], 1);
    atomicAdd(&deg0[clampN(h.y)], 1);
    atomicAdd(&deg0[clampN(h.z)], 1);
    atomicAdd(&deg0[clampN(h.w)], 1);
}

// In-block exclusive scan of 256 ints; also zeroes cursor for edge_scatter.
__global__ void scan_local(const int* __restrict__ deg0, int* __restrict__ offsets,
                           int* __restrict__ bsum, int* __restrict__ cursor) {
    int gid = blockIdx.x * 256 + threadIdx.x;
    int lane = threadIdx.x & 63, w = threadIdx.x >> 6;
    int vdeg = (gid < NN) ? deg0[gid] : 0;
    if (gid < NN) cursor[gid] = 0;
    int x = vdeg;
    #pragma unroll
    for (int d = 1; d < 64; d <<= 1) {
        int y = __shfl_up(x, d, 64);
        if (lane >= d) x += y;
    }
    __shared__ int wsum[4];
    if (lane == 63) wsum[w] = x;
    __syncthreads();
    int wpre = 0;
    #pragma unroll
    for (int j = 0; j < 4; ++j) wpre += (j < w) ? wsum[j] : 0;
    int incl = x + wpre;
    if (gid < NN) offsets[gid] = incl - vdeg;
    if (threadIdx.x == 255) bsum[blockIdx.x] = incl;
}

// Each block re-scans the 235 block sums (cheap) and adds its own prefix.
__global__ void scan_add2(int* __restrict__ offsets, const int* __restrict__ bsum) {
    int tid = threadIdx.x, lane = tid & 63, w = tid >> 6;
    int vv = (tid < SCAN_B) ? bsum[tid] : 0;
    int x = vv;
    #pragma unroll
    for (int d = 1; d < 64; d <<= 1) {
        int y = __shfl_up(x, d, 64);
        if (lane >= d) x += y;
    }
    __shared__ int wsum[4];
    __shared__ int bpre;
    if (lane == 63) wsum[w] = x;
    __syncthreads();
    int wpre = 0;
    #pragma unroll
    for (int j = 0; j < 4; ++j) wpre += (j < w) ? wsum[j] : 0;
    if (tid == blockIdx.x) bpre = x + wpre - vv;   // exclusive prefix of this block
    __syncthreads();
    int gid = blockIdx.x * 256 + tid;
    if (gid < NN) offsets[gid] += bpre;
    if (gid == 0) offsets[NN] = EE;
}

__global__ void edge_scatter(const int* __restrict__ eh, const int* __restrict__ et,
                             const int* __restrict__ offsets, int* __restrict__ cursor,
                             int* __restrict__ csr_tail) {
    int e4 = (blockIdx.x * blockDim.x + threadIdx.x) * 4;
    if (e4 >= EE) return;
    int4 h = *(const int4*)(eh + e4);
    int4 t = *(const int4*)(et + e4);
    int h0 = clampN(h.x), h1 = clampN(h.y), h2 = clampN(h.z), h3 = clampN(h.w);
    int s0 = offsets[h0] + atomicAdd(&cursor[h0], 1);
    if (s0 < EE) csr_tail[s0] = clampN(t.x);
    int s1 = offsets[h1] + atomicAdd(&cursor[h1], 1);
    if (s1 < EE) csr_tail[s1] = clampN(t.y);
    int s2 = offsets[h2] + atomicAdd(&cursor[h2], 1);
    if (s2 < EE) csr_tail[s2] = clampN(t.z);
    int s3 = offsets[h3] + atomicAdd(&cursor[h3], 1);
    if (s3 < EE) csr_tail[s3] = clampN(t.w);
}

// ---- node-side precompute: YT[i][n][cp] = {Y quad, T quad}, + zero row n==NN ----

__global__ void prep0s(const float* __restrict__ Gu, const float* __restrict__ Gi,
                       const int* __restrict__ deg0, __half* __restrict__ YT) {
    int n = blockIdx.x * 4 + (threadIdx.x >> 6);
    if (n > NN) return;
    int lane = threadIdx.x & 63;
    int i = lane >> 4, ch = lane & 15;
    float x = (n < NN) ? getX(Gu, Gi, n, lane) : 0.f;
    float sx = x * x;
    #pragma unroll
    for (int m = 1; m < 16; m <<= 1) sx += __shfl_xor(sx, m, 64);
    float invx = rsqrtf(fmaxf(sx, 1e-12f));
    float d0 = rsqrtf(fmaxf(0.25f * (float)((n < NN) ? deg0[n] : 1), 1e-30f));
    size_t a = (size_t)i * SLY + (size_t)n * 32 + (size_t)(ch >> 2) * 8 + (ch & 3);
    YT[a]     = __float2half(d0 * x);          // Y quad slot
    YT[a + 4] = __float2half(tanhf(x * invx)); // T quad slot
}

// ---- fused pinned pass: Z1 accumulate + l2norm + attention dots ----
// Wave = (node, intent); lane = (edge slot e4 = lane>>2) x (ch-quad cp = lane&3).
// deg<=32 fast path: ONE dwordx4/lane/edge fetches Y+T; T cached in regs.
__global__ void fused_attn(const int* __restrict__ offsets, const int* __restrict__ csr_tail,
                           const __half* __restrict__ YT, __half* __restrict__ v) {
    int i;
    int n = pinnedNode(blockIdx.x, threadIdx.x, &i);
    int lane = threadIdx.x & 63;
    int e4 = lane >> 2, cp = lane & 3;
    int s0 = offsets[n], s1 = offsets[n + 1];
    int deg = s1 - s0;
    const __half* Yi = YT + (size_t)i * SLY;
    const __half2 h2z = __floats2half2_rn(0.f, 0.f);

    __half2 z0 = h2z, z1 = h2z;
    __half2 tA0 = h2z, tA1 = h2z, tB0 = h2z, tB1 = h2z;
    bool actA = false, actB = false;
    bool fast = (deg <= 32);

    if (fast) {
        int kkA = s0 + e4; actA = kkA < s1;
        int tA = actA ? csr_tail[kkA] : NN;                 // NN = zero row
        const __half2* rA = (const __half2*)(Yi + (size_t)tA * 32 + cp * 8);
        z0 = rA[0]; z1 = rA[1]; tA0 = rA[2]; tA1 = rA[3];
        if (deg > 16) {
            int kkB = s0 + 16 + e4; actB = kkB < s1;
            int tB = actB ? csr_tail[kkB] : NN;
            const __half2* rB = (const __half2*)(Yi + (size_t)tB * 32 + cp * 8);
            z0 = __hadd2(z0, rB[0]); z1 = __hadd2(z1, rB[1]);
            tB0 = rB[2]; tB1 = rB[3];
        }
    } else {
        for (int base = s0; base < s1; base += 16) {
            int kk = base + e4;
            int t = (kk < s1) ? csr_tail[kk] : NN;
            const __half2* r = (const __half2*)(Yi + (size_t)t * 32 + cp * 8);
            z0 = __hadd2(z0, r[0]); z1 = __hadd2(z1, r[1]);
        }
    }
    // reduce across 16 edge slots; all lanes active
    #pragma unroll
    for (int m = 4; m < 64; m <<= 1) {
        z0 = __hadd2(z0, shfl_xor_h2(z0, m));
        z1 = __hadd2(z1, shfl_xor_h2(z1, m));
    }
    float2 f0 = __half22float2(z0), f1 = __half22float2(z1);
    float ss = f0.x * f0.x + f0.y * f0.y + f1.x * f1.x + f1.y * f1.y;
    ss += __shfl_xor(ss, 1, 64);
    ss += __shfl_xor(ss, 2, 64);
    float inv = rsqrtf(fmaxf(ss, 1e-12f));
    __half2 zn0 = __floats2half2_rn(f0.x * inv, f0.y * inv);
    __half2 zn1 = __floats2half2_rn(f1.x * inv, f1.y * inv);

    __half* vi = v + (size_t)i * EE;
    if (fast) {
        __half2 d2 = __hmul2(zn0, tA0); d2 = __hfma2(zn1, tA1, d2);
        float2 df = __half22float2(d2);
        float p = df.x + df.y;
        p += __shfl_xor(p, 1, 64);
        p += __shfl_xor(p, 2, 64);
        if (actA && cp == 0) vi[s0 + e4] = __float2half(p);
        if (deg > 16) {
            __half2 e2 = __hmul2(zn0, tB0); e2 = __hfma2(zn1, tB1, e2);
            float2 ef = __half22float2(e2);
            float q = ef.x + ef.y;
            q += __shfl_xor(q, 1, 64);
            q += __shfl_xor(q, 2, 64);
            if (actB && cp == 0) vi[s0 + 16 + e4] = __float2half(q);
        }
    } else {
        for (int base = s0; base < s1; base += 16) {
            int kk = base + e4;
            bool act = kk < s1;
            int t = act ? csr_tail[kk] : NN;
            const __half2* r = (const __half2*)(Yi + (size_t)t * 32 + cp * 8 + 4);
            __half2 d2 = __hmul2(zn0, r[0]); d2 = __hfma2(zn1, r[1], d2);
            float2 df = __half22float2(d2);
            float p = df.x + df.y;
            p += __shfl_xor(p, 1, 64);
            p += __shfl_xor(p, 2, 64);
            if (act && cp == 0) vi[kk] = __float2half(p);
        }
    }
}

// ---- fused softmax + deg1 + dcol1 + Y1s build (wave per node) ----
__global__ void sm_dcol_y1(const int* __restrict__ offsets, const __half* __restrict__ v,
                           __half* __restrict__ scores, float* __restrict__ dcol1,
                           const float* __restrict__ Gu, const float* __restrict__ Gi,
                           __half* __restrict__ Y1s) {
    int n = blockIdx.x * 4 + (threadIdx.x >> 6);
    if (n >= NN) return;
    int lane = threadIdx.x & 63;
    int s0 = offsets[n], s1 = offsets[n + 1];
    float sum0 = 0.f, sum1 = 0.f, sum2 = 0.f, sum3 = 0.f;
    for (int k = s0 + lane; k < s1; k += 64) {
        float v0 = __half2float(v[k]);
        float v1 = __half2float(v[EE + k]);
        float v2 = __half2float(v[2 * EE + k]);
        float v3 = __half2float(v[3 * EE + k]);
        float mx = fmaxf(fmaxf(v0, v1), fmaxf(v2, v3));
        float e0 = __expf(v0 - mx), e1 = __expf(v1 - mx);
        float e2 = __expf(v2 - mx), e3 = __expf(v3 - mx);
        float inv = 1.f / (e0 + e1 + e2 + e3);
        e0 *= inv; e1 *= inv; e2 *= inv; e3 *= inv;
        scores[k]          = __float2half(e0);
        scores[EE + k]     = __float2half(e1);
        scores[2 * EE + k] = __float2half(e2);
        scores[3 * EE + k] = __float2half(e3);
        sum0 += e0; sum1 += e1; sum2 += e2; sum3 += e3;
    }
    #pragma unroll
    for (int m = 1; m < 64; m <<= 1) {
        sum0 += __shfl_xor(sum0, m, 64);
        sum1 += __shfl_xor(sum1, m, 64);
        sum2 += __shfl_xor(sum2, m, 64);
        sum3 += __shfl_xor(sum3, m, 64);
    }
    int i = lane >> 4, ch = lane & 15;
    float dsel = (i == 0) ? sum0 : (i == 1) ? sum1 : (i == 2) ? sum2 : sum3;
    float d = rsqrtf(fmaxf(dsel, 1e-30f));
    if (lane < 4) {
        float ds = (lane == 0) ? sum0 : (lane == 1) ? sum1 : (lane == 2) ? sum2 : sum3;
        dcol1[n * 4 + lane] = rsqrtf(fmaxf(ds, 1e-30f));
    }
    float x = getX(Gu, Gi, n, lane);
    Y1s[(size_t)i * SL + (size_t)n * 16 + ch] = __float2half(d * x);
}

// ---- pinned output pass: Z2 gather + finalize ----
// deg<=32 fast path; inactive slots use s=0 (t=0 row is finite). Packed
// half2 cross-slot reduce (fp32 accumulate inside bursts).
__global__ void outk(const int* __restrict__ offsets, const int* __restrict__ csr_tail,
                     const __half* __restrict__ Y1s, const __half* __restrict__ scores,
                     const float* __restrict__ dcol1,
                     const float* __restrict__ Gu, const float* __restrict__ Gi,
                     float* __restrict__ out) {
    int i;
    int n = pinnedNode(blockIdx.x, threadIdx.x, &i);
    int lane = threadIdx.x & 63;
    int e4 = lane >> 2, cp = lane & 3;
    int s0 = offsets[n], s1 = offsets[n + 1];
    int deg = s1 - s0;
    const __half* Yi = Y1s + (size_t)i * SL;
    const __half* si = scores + (size_t)i * EE;

    float a0, a1, a2, a3;
    if (deg <= 32) {
        int kkA = s0 + e4;
        bool actA = kkA < s1;
        int tA = actA ? csr_tail[kkA] : 0;
        float sA = actA ? __half2float(si[kkA]) : 0.f;
        const __half2* rA = (const __half2*)(Yi + (size_t)tA * 16 + cp * 4);
        float2 r0 = __half22float2(rA[0]), r1 = __half22float2(rA[1]);
        a0 = sA * r0.x; a1 = sA * r0.y; a2 = sA * r1.x; a3 = sA * r1.y;
        if (deg > 16) {
            int kkB = s0 + 16 + e4;
            bool actB = kkB < s1;
            int tB = actB ? csr_tail[kkB] : 0;
            float sB = actB ? __half2float(si[kkB]) : 0.f;
            const __half2* rB = (const __half2*)(Yi + (size_t)tB * 16 + cp * 4);
            float2 q0 = __half22float2(rB[0]), q1 = __half22float2(rB[1]);
            a0 += sB * q0.x; a1 += sB * q0.y; a2 += sB * q1.x; a3 += sB * q1.y;
        }
    } else {
        a0 = a1 = a2 = a3 = 0.f;
        for (int base = s0; base < s1; base += 16) {
            int kk = base + e4;
            bool act = kk < s1;
            int t = act ? csr_tail[kk] : 0;
            float s = act ? __half2float(si[kk]) : 0.f;
            const __half2* row = (const __half2*)(Yi + (size_t)t * 16 + cp * 4);
            float2 r0 = __half22float2(row[0]), r1 = __half22float2(row[1]);
            a0 += s * r0.x; a1 += s * r0.y; a2 += s * r1.x; a3 += s * r1.y;
        }
    }
    // packed cross-slot reduce (16 slots): 2 half2 regs, 4 butterfly steps
    __half2 p0 = __floats2half2_rn(a0, a1);
    __half2 p1 = __floats2half2_rn(a2, a3);
    #pragma unroll
    for (int m = 4; m < 64; m <<= 1) {
        p0 = __hadd2(p0, shfl_xor_h2(p0, m));
        p1 = __hadd2(p1, shfl_xor_h2(p1, m));
    }
    if (e4 == 0) {
        float2 q0 = __half22float2(p0), q1 = __half22float2(p1);
        int c = i * 16 + cp * 4;
        const float* xr = (n < NUSERS) ? (Gu + n * 64 + c) : (Gi + (n - NUSERS) * 64 + c);
        float4 x4 = *(const float4*)xr;
        float d = dcol1[n * 4 + i];
        float4 o;
        o.x = 0.5f * (x4.x + d * q0.x);
        o.y = 0.5f * (x4.y + d * q0.y);
        o.z = 0.5f * (x4.z + d * q1.x);
        o.w = 0.5f * (x4.w + d * q1.y);
        *(float4*)(out + (size_t)n * 64 + c) = o;
    }
}

// ---- launch ----

extern "C" void kernel_launch(void* const* d_in, const int* in_sizes, int n_in,
                              void* d_out, int out_size, void* d_ws, size_t ws_size,
                              hipStream_t stream) {
    const float* Gu = (const float*)d_in[0];
    const float* Gi = (const float*)d_in[1];
    const int* eh = (const int*)d_in[2];
    const int* et = (const int*)d_in[3];
    float* out = (float*)d_out;

    char* p = (char*)d_ws;
    __half* v        = (__half*)p;     p += (size_t)EE * 4 * 2;       // 6.4 MB
    __half* scores   = (__half*)p;     p += (size_t)EE * 4 * 2;       // 6.4 MB
    int*    csr_tail = (int*)p;        p += (size_t)EE * 4;           // 3.2 MB
    int*    offsets  = (int*)p;        p += ((size_t)(NN + 1) * 4 + 15) / 16 * 16;
    int*    deg0     = (int*)p;        p += (size_t)NN * 4;
    int*    cursor   = (int*)p;        p += (size_t)NN * 4;
    int*    bsum     = (int*)p;        p += ((size_t)SCAN_B * 4 + 15) / 16 * 16;
    float*  dcol1    = (float*)p;      p += (size_t)NN * 4 * 4;
    __half* YT       = (__half*)p;     // 4*SLY*2 = 15.36 MB -> total ~33 MB
    __half* Y1s      = YT;             // aliases YT (YT last read in fused_attn)

    const int ev_blocks   = (EE / 4 + 255) / 256;   // int4-vectorized edge kernels
    const int nw_blocks   = (NN + 3) / 4;
    const int nw1_blocks  = (NN + 1 + 3) / 4;       // covers zero row n==NN
    const int sl_blocks   = NN;        // 15000 node-groups x 4 intents (pinned)

    // CSR build
    hipMemsetAsync(deg0, 0, NN * sizeof(int), stream);
    edge_count<<<ev_blocks, 256, 0, stream>>>(eh, deg0);
    scan_local<<<SCAN_B, 256, 0, stream>>>(deg0, offsets, bsum, cursor);
    scan_add2<<<SCAN_B, 256, 0, stream>>>(offsets, bsum);
    edge_scatter<<<ev_blocks, 256, 0, stream>>>(eh, et, offsets, cursor, csr_tail);

    // iter 0: interleaved YT table + fused Z1/attention
    prep0s<<<nw1_blocks, 256, 0, stream>>>(Gu, Gi, deg0, YT);
    fused_attn<<<sl_blocks, 256, 0, stream>>>(offsets, csr_tail, YT, v);

    // softmax + dcol1 + Y1s in one pass
    sm_dcol_y1<<<nw_blocks, 256, 0, stream>>>(offsets, v, scores, dcol1, Gu, Gi, Y1s);

    // iter 1 propagate + finalize
    outk<<<sl_blocks, 256, 0, stream>>>(offsets, csr_tail, Y1s, scores, dcol1, Gu, Gi, out);
}

// Round 14
// 308.023 us; speedup vs baseline: 1.9475x; 1.0211x over previous
//
#include <hip/hip_runtime.h>
#include <hip/hip_fp16.h>

// DGCF single-layer, 2 routing iters (MI355X). fp32 in / fp32 out.
// R13 post-mortem: outk fast path was neutral (80->77us): per-edge VALU
// (2 cvt + 4 fp32 fma + loads) unchanged; VALUBusy 43% = ~33us pure issue.
// R14:
//  - outk: packed half2 accumulate -- score broadcast + 2 __hfma2/edge,
//    half2 accumulators straight into the butterfly reduce (no pack)
//  - edge_scatter || prep0s merged into one dispatch (block-range split):
//    scatter is atomic-latency-bound, prep0s VALU-bound -> co-scheduled
// Unchanged from R13 (passing): YT interleaved table, fused_attn fast path,
// int4 edge kernels, parallel scan, sm_dcol_y1, [intent][E] streams, pinning.

#define NUSERS 30000
#define NN     60000
#define EE     800000
#define SL     ((size_t)NN * 16)        // Y1s slice elements
#define SLY    ((size_t)(NN + 1) * 32)  // YT slice elements (+ zero row)
#define SCAN_B ((NN + 255) / 256)       // 235 scan blocks
#define EV_B   ((EE / 4 + 255) / 256)   // 782 int4 edge blocks
#define NW1_B  ((NN + 1 + 3) / 4)       // 15001 node blocks (incl zero row)

__device__ __forceinline__ float getX(const float* __restrict__ Gu,
                                      const float* __restrict__ Gi,
                                      int n, int c) {
    return (n < NUSERS) ? Gu[n * 64 + c] : Gi[(n - NUSERS) * 64 + c];
}

__device__ __forceinline__ int clampN(int n) {
    return ((unsigned)n < (unsigned)NN) ? n : 0;
}

__device__ __forceinline__ __half2 shfl_xor_h2(__half2 x, int m) {
    int xi = __builtin_bit_cast(int, x);
    xi = __shfl_xor(xi, m, 64);
    return __builtin_bit_cast(__half2, xi);
}

// Pinned-block index decode: blockIdx b -> intent i (XCD pair), node n.
__device__ __forceinline__ int pinnedNode(int b, int tid, int* i) {
    int xcd = b & 7;
    *i = xcd >> 1;
    int g = (b >> 3) * 2 + (xcd & 1);          // node-group in [0,15000)
    return g * 4 + (tid >> 6);
}

// ---- CSR build ----

__global__ void edge_count(const int* __restrict__ eh, int* __restrict__ deg0) {
    int e4 = (blockIdx.x * blockDim.x + threadIdx.x) * 4;
    if (e4 >= EE) return;
    int4 h = *(const int4*)(eh + e4);
    atomicAdd(&deg0[clampN(h.x)], 1);
    atomicAdd(&deg0[clampN(h.y)], 1);
    atomicAdd(&deg0[clampN(h.z)], 1);
    atomicAdd(&deg0[clampN(h.w)], 1);
}

// In-block exclusive scan of 256 ints; also zeroes cursor for edge_scatter.
__global__ void scan_local(const int* __restrict__ deg0, int* __restrict__ offsets,
                           int* __restrict__ bsum, int* __restrict__ cursor) {
    int gid = blockIdx.x * 256 + threadIdx.x;
    int lane = threadIdx.x & 63, w = threadIdx.x >> 6;
    int vdeg = (gid < NN) ? deg0[gid] : 0;
    if (gid < NN) cursor[gid] = 0;
    int x = vdeg;
    #pragma unroll
    for (int d = 1; d < 64; d <<= 1) {
        int y = __shfl_up(x, d, 64);
        if (lane >= d) x += y;
    }
    __shared__ int wsum[4];
    if (lane == 63) wsum[w] = x;
    __syncthreads();
    int wpre = 0;
    #pragma unroll
    for (int j = 0; j < 4; ++j) wpre += (j < w) ? wsum[j] : 0;
    int incl = x + wpre;
    if (gid < NN) offsets[gid] = incl - vdeg;
    if (threadIdx.x == 255) bsum[blockIdx.x] = incl;
}

// Each block re-scans the 235 block sums (cheap) and adds its own prefix.
__global__ void scan_add2(int* __restrict__ offsets, const int* __restrict__ bsum) {
    int tid = threadIdx.x, lane = tid & 63, w = tid >> 6;
    int vv = (tid < SCAN_B) ? bsum[tid] : 0;
    int x = vv;
    #pragma unroll
    for (int d = 1; d < 64; d <<= 1) {
        int y = __shfl_up(x, d, 64);
        if (lane >= d) x += y;
    }
    __shared__ int wsum[4];
    __shared__ int bpre;
    if (lane == 63) wsum[w] = x;
    __syncthreads();
    int wpre = 0;
    #pragma unroll
    for (int j = 0; j < 4; ++j) wpre += (j < w) ? wsum[j] : 0;
    if (tid == blockIdx.x) bpre = x + wpre - vv;   // exclusive prefix of this block
    __syncthreads();
    int gid = blockIdx.x * 256 + tid;
    if (gid < NN) offsets[gid] += bpre;
    if (gid == 0) offsets[NN] = EE;
}

// ---- merged dispatch: edge_scatter (blocks [0,EV_B)) || prep0s (rest) ----
// Independent work, different bottlenecks (atomic latency vs VALU tanh):
// co-scheduling hides prep0s under scatter.
__global__ void scatter_prep(const int* __restrict__ eh, const int* __restrict__ et,
                             const int* __restrict__ offsets, int* __restrict__ cursor,
                             int* __restrict__ csr_tail,
                             const float* __restrict__ Gu, const float* __restrict__ Gi,
                             const int* __restrict__ deg0, __half* __restrict__ YT) {
    if (blockIdx.x < EV_B) {
        int e4 = (blockIdx.x * 256 + threadIdx.x) * 4;
        if (e4 >= EE) return;
        int4 h = *(const int4*)(eh + e4);
        int4 t = *(const int4*)(et + e4);
        int h0 = clampN(h.x), h1 = clampN(h.y), h2 = clampN(h.z), h3 = clampN(h.w);
        int s0 = offsets[h0] + atomicAdd(&cursor[h0], 1);
        if (s0 < EE) csr_tail[s0] = clampN(t.x);
        int s1 = offsets[h1] + atomicAdd(&cursor[h1], 1);
        if (s1 < EE) csr_tail[s1] = clampN(t.y);
        int s2 = offsets[h2] + atomicAdd(&cursor[h2], 1);
        if (s2 < EE) csr_tail[s2] = clampN(t.z);
        int s3 = offsets[h3] + atomicAdd(&cursor[h3], 1);
        if (s3 < EE) csr_tail[s3] = clampN(t.w);
    } else {
        // prep0s: YT[i][n][cp] = {Y quad | T quad}, zero row at n == NN
        int n = (blockIdx.x - EV_B) * 4 + (threadIdx.x >> 6);
        if (n > NN) return;
        int lane = threadIdx.x & 63;
        int i = lane >> 4, ch = lane & 15;
        float x = (n < NN) ? getX(Gu, Gi, n, lane) : 0.f;
        float sx = x * x;
        #pragma unroll
        for (int m = 1; m < 16; m <<= 1) sx += __shfl_xor(sx, m, 64);
        float invx = rsqrtf(fmaxf(sx, 1e-12f));
        float d0 = rsqrtf(fmaxf(0.25f * (float)((n < NN) ? deg0[n] : 1), 1e-30f));
        size_t a = (size_t)i * SLY + (size_t)n * 32 + (size_t)(ch >> 2) * 8 + (ch & 3);
        YT[a]     = __float2half(d0 * x);          // Y quad slot
        YT[a + 4] = __float2half(tanhf(x * invx)); // T quad slot
    }
}

// ---- fused pinned pass: Z1 accumulate + l2norm + attention dots ----
__global__ void fused_attn(const int* __restrict__ offsets, const int* __restrict__ csr_tail,
                           const __half* __restrict__ YT, __half* __restrict__ v) {
    int i;
    int n = pinnedNode(blockIdx.x, threadIdx.x, &i);
    int lane = threadIdx.x & 63;
    int e4 = lane >> 2, cp = lane & 3;
    int s0 = offsets[n], s1 = offsets[n + 1];
    int deg = s1 - s0;
    const __half* Yi = YT + (size_t)i * SLY;
    const __half2 h2z = __floats2half2_rn(0.f, 0.f);

    __half2 z0 = h2z, z1 = h2z;
    __half2 tA0 = h2z, tA1 = h2z, tB0 = h2z, tB1 = h2z;
    bool actA = false, actB = false;
    bool fast = (deg <= 32);

    if (fast) {
        int kkA = s0 + e4; actA = kkA < s1;
        int tA = actA ? csr_tail[kkA] : NN;                 // NN = zero row
        const __half2* rA = (const __half2*)(Yi + (size_t)tA * 32 + cp * 8);
        z0 = rA[0]; z1 = rA[1]; tA0 = rA[2]; tA1 = rA[3];
        if (deg > 16) {
            int kkB = s0 + 16 + e4; actB = kkB < s1;
            int tB = actB ? csr_tail[kkB] : NN;
            const __half2* rB = (const __half2*)(Yi + (size_t)tB * 32 + cp * 8);
            z0 = __hadd2(z0, rB[0]); z1 = __hadd2(z1, rB[1]);
            tB0 = rB[2]; tB1 = rB[3];
        }
    } else {
        for (int base = s0; base < s1; base += 16) {
            int kk = base + e4;
            int t = (kk < s1) ? csr_tail[kk] : NN;
            const __half2* r = (const __half2*)(Yi + (size_t)t * 32 + cp * 8);
            z0 = __hadd2(z0, r[0]); z1 = __hadd2(z1, r[1]);
        }
    }
    #pragma unroll
    for (int m = 4; m < 64; m <<= 1) {
        z0 = __hadd2(z0, shfl_xor_h2(z0, m));
        z1 = __hadd2(z1, shfl_xor_h2(z1, m));
    }
    float2 f0 = __half22float2(z0), f1 = __half22float2(z1);
    float ss = f0.x * f0.x + f0.y * f0.y + f1.x * f1.x + f1.y * f1.y;
    ss += __shfl_xor(ss, 1, 64);
    ss += __shfl_xor(ss, 2, 64);
    float inv = rsqrtf(fmaxf(ss, 1e-12f));
    __half2 zn0 = __floats2half2_rn(f0.x * inv, f0.y * inv);
    __half2 zn1 = __floats2half2_rn(f1.x * inv, f1.y * inv);

    __half* vi = v + (size_t)i * EE;
    if (fast) {
        __half2 d2 = __hmul2(zn0, tA0); d2 = __hfma2(zn1, tA1, d2);
        float2 df = __half22float2(d2);
        float p = df.x + df.y;
        p += __shfl_xor(p, 1, 64);
        p += __shfl_xor(p, 2, 64);
        if (actA && cp == 0) vi[s0 + e4] = __float2half(p);
        if (deg > 16) {
            __half2 e2 = __hmul2(zn0, tB0); e2 = __hfma2(zn1, tB1, e2);
            float2 ef = __half22float2(e2);
            float q = ef.x + ef.y;
            q += __shfl_xor(q, 1, 64);
            q += __shfl_xor(q, 2, 64);
            if (actB && cp == 0) vi[s0 + 16 + e4] = __float2half(q);
        }
    } else {
        for (int base = s0; base < s1; base += 16) {
            int kk = base + e4;
            bool act = kk < s1;
            int t = act ? csr_tail[kk] : NN;
            const __half2* r = (const __half2*)(Yi + (size_t)t * 32 + cp * 8 + 4);
            __half2 d2 = __hmul2(zn0, r[0]); d2 = __hfma2(zn1, r[1], d2);
            float2 df = __half22float2(d2);
            float p = df.x + df.y;
            p += __shfl_xor(p, 1, 64);
            p += __shfl_xor(p, 2, 64);
            if (act && cp == 0) vi[kk] = __float2half(p);
        }
    }
}

// ---- fused softmax + deg1 + dcol1 + Y1s build (wave per node) ----
__global__ void sm_dcol_y1(const int* __restrict__ offsets, const __half* __restrict__ v,
                           __half* __restrict__ scores, float* __restrict__ dcol1,
                           const float* __restrict__ Gu, const float* __restrict__ Gi,
                           __half* __restrict__ Y1s) {
    int n = blockIdx.x * 4 + (threadIdx.x >> 6);
    if (n >= NN) return;
    int lane = threadIdx.x & 63;
    int s0 = offsets[n], s1 = offsets[n + 1];
    float sum0 = 0.f, sum1 = 0.f, sum2 = 0.f, sum3 = 0.f;
    for (int k = s0 + lane; k < s1; k += 64) {
        float v0 = __half2float(v[k]);
        float v1 = __half2float(v[EE + k]);
        float v2 = __half2float(v[2 * EE + k]);
        float v3 = __half2float(v[3 * EE + k]);
        float mx = fmaxf(fmaxf(v0, v1), fmaxf(v2, v3));
        float e0 = __expf(v0 - mx), e1 = __expf(v1 - mx);
        float e2 = __expf(v2 - mx), e3 = __expf(v3 - mx);
        float inv = 1.f / (e0 + e1 + e2 + e3);
        e0 *= inv; e1 *= inv; e2 *= inv; e3 *= inv;
        scores[k]          = __float2half(e0);
        scores[EE + k]     = __float2half(e1);
        scores[2 * EE + k] = __float2half(e2);
        scores[3 * EE + k] = __float2half(e3);
        sum0 += e0; sum1 += e1; sum2 += e2; sum3 += e3;
    }
    #pragma unroll
    for (int m = 1; m < 64; m <<= 1) {
        sum0 += __shfl_xor(sum0, m, 64);
        sum1 += __shfl_xor(sum1, m, 64);
        sum2 += __shfl_xor(sum2, m, 64);
        sum3 += __shfl_xor(sum3, m, 64);
    }
    int i = lane >> 4, ch = lane & 15;
    float dsel = (i == 0) ? sum0 : (i == 1) ? sum1 : (i == 2) ? sum2 : sum3;
    float d = rsqrtf(fmaxf(dsel, 1e-30f));
    if (lane < 4) {
        float ds = (lane == 0) ? sum0 : (lane == 1) ? sum1 : (lane == 2) ? sum2 : sum3;
        dcol1[n * 4 + lane] = rsqrtf(fmaxf(ds, 1e-30f));
    }
    float x = getX(Gu, Gi, n, lane);
    Y1s[(size_t)i * SL + (size_t)n * 16 + ch] = __float2half(d * x);
}

// ---- pinned output pass: Z2 gather + finalize ----
// Packed half2 accumulate: score broadcast + 2 hfma2 per edge-visit.
__global__ void outk(const int* __restrict__ offsets, const int* __restrict__ csr_tail,
                     const __half* __restrict__ Y1s, const __half* __restrict__ scores,
                     const float* __restrict__ dcol1,
                     const float* __restrict__ Gu, const float* __restrict__ Gi,
                     float* __restrict__ out) {
    int i;
    int n = pinnedNode(blockIdx.x, threadIdx.x, &i);
    int lane = threadIdx.x & 63;
    int e4 = lane >> 2, cp = lane & 3;
    int s0 = offsets[n], s1 = offsets[n + 1];
    int deg = s1 - s0;
    const __half* Yi = Y1s + (size_t)i * SL;
    const __half* si = scores + (size_t)i * EE;
    const __half hz = __float2half(0.f);
    const __half2 h2z = __half2half2(hz);

    __half2 acc0 = h2z, acc1 = h2z;
    if (deg <= 32) {
        int kkA = s0 + e4;
        bool actA = kkA < s1;
        int tA = actA ? csr_tail[kkA] : 0;
        __half2 sa = __half2half2(actA ? si[kkA] : hz);
        const __half2* rA = (const __half2*)(Yi + (size_t)tA * 16 + cp * 4);
        acc0 = __hmul2(sa, rA[0]);
        acc1 = __hmul2(sa, rA[1]);
        if (deg > 16) {
            int kkB = s0 + 16 + e4;
            bool actB = kkB < s1;
            int tB = actB ? csr_tail[kkB] : 0;
            __half2 sb = __half2half2(actB ? si[kkB] : hz);
            const __half2* rB = (const __half2*)(Yi + (size_t)tB * 16 + cp * 4);
            acc0 = __hfma2(sb, rB[0], acc0);
            acc1 = __hfma2(sb, rB[1], acc1);
        }
    } else {
        for (int base = s0; base < s1; base += 16) {
            int kk = base + e4;
            bool act = kk < s1;
            int t = act ? csr_tail[kk] : 0;
            __half2 sh = __half2half2(act ? si[kk] : hz);
            const __half2* row = (const __half2*)(Yi + (size_t)t * 16 + cp * 4);
            acc0 = __hfma2(sh, row[0], acc0);
            acc1 = __hfma2(sh, row[1], acc1);
        }
    }
    // cross-slot reduce (16 slots): 2 half2 regs, 4 butterfly steps
    #pragma unroll
    for (int m = 4; m < 64; m <<= 1) {
        acc0 = __hadd2(acc0, shfl_xor_h2(acc0, m));
        acc1 = __hadd2(acc1, shfl_xor_h2(acc1, m));
    }
    if (e4 == 0) {
        float2 q0 = __half22float2(acc0), q1 = __half22float2(acc1);
        int c = i * 16 + cp * 4;
        const float* xr = (n < NUSERS) ? (Gu + n * 64 + c) : (Gi + (n - NUSERS) * 64 + c);
        float4 x4 = *(const float4*)xr;
        float d = dcol1[n * 4 + i];
        float4 o;
        o.x = 0.5f * (x4.x + d * q0.x);
        o.y = 0.5f * (x4.y + d * q0.y);
        o.z = 0.5f * (x4.z + d * q1.x);
        o.w = 0.5f * (x4.w + d * q1.y);
        *(float4*)(out + (size_t)n * 64 + c) = o;
    }
}

// ---- launch ----

extern "C" void kernel_launch(void* const* d_in, const int* in_sizes, int n_in,
                              void* d_out, int out_size, void* d_ws, size_t ws_size,
                              hipStream_t stream) {
    const float* Gu = (const float*)d_in[0];
    const float* Gi = (const float*)d_in[1];
    const int* eh = (const int*)d_in[2];
    const int* et = (const int*)d_in[3];
    float* out = (float*)d_out;

    char* p = (char*)d_ws;
    __half* v        = (__half*)p;     p += (size_t)EE * 4 * 2;       // 6.4 MB
    __half* scores   = (__half*)p;     p += (size_t)EE * 4 * 2;       // 6.4 MB
    int*    csr_tail = (int*)p;        p += (size_t)EE * 4;           // 3.2 MB
    int*    offsets  = (int*)p;        p += ((size_t)(NN + 1) * 4 + 15) / 16 * 16;
    int*    deg0     = (int*)p;        p += (size_t)NN * 4;
    int*    cursor   = (int*)p;        p += (size_t)NN * 4;
    int*    bsum     = (int*)p;        p += ((size_t)SCAN_B * 4 + 15) / 16 * 16;
    float*  dcol1    = (float*)p;      p += (size_t)NN * 4 * 4;
    __half* YT       = (__half*)p;     // 4*SLY*2 = 15.36 MB -> total ~33 MB
    __half* Y1s      = YT;             // aliases YT (YT last read in fused_attn)

    const int nw_blocks = (NN + 3) / 4;
    const int sl_blocks = NN;          // 15000 node-groups x 4 intents (pinned)

    // CSR build
    hipMemsetAsync(deg0, 0, NN * sizeof(int), stream);
    edge_count<<<EV_B, 256, 0, stream>>>(eh, deg0);
    scan_local<<<SCAN_B, 256, 0, stream>>>(deg0, offsets, bsum, cursor);
    scan_add2<<<SCAN_B, 256, 0, stream>>>(offsets, bsum);

    // edge_scatter || prep0s (independent; co-scheduled in one dispatch)
    scatter_prep<<<EV_B + NW1_B, 256, 0, stream>>>(eh, et, offsets, cursor, csr_tail,
                                                   Gu, Gi, deg0, YT);

    // iter 0: fused Z1/attention
    fused_attn<<<sl_blocks, 256, 0, stream>>>(offsets, csr_tail, YT, v);

    // softmax + dcol1 + Y1s in one pass
    sm_dcol_y1<<<nw_blocks, 256, 0, stream>>>(offsets, v, scores, dcol1, Gu, Gi, Y1s);

    // iter 1 propagate + finalize
    outk<<<sl_blocks, 256, 0, stream>>>(offsets, csr_tail, Y1s, scores, dcol1, Gu, Gi, out);
}